// Round 2
// baseline (12112.685 us; speedup 1.0000x reference)
//
#include <hip/hip_runtime.h>
#include <hip/hip_bf16.h>
#include <cstddef>

typedef __hip_bfloat16 bf16;
#define DEV static __device__ __forceinline__

constexpr int NB = 16;     // batch
constexpr int SEQL = 20;
constexpr int CD = 256;    // VD
constexpr int PP = 1024;   // 32*32
constexpr int HND = 512;
constexpr int EMBD = 300;
constexpr int CIN = 776;   // 256 + 8 + 512

// ---- workspace layout (float element offsets) ----
constexpr size_t SZ_NPC = (size_t)NB * PP * CD;              // 4,194,304
constexpr size_t OF_FEAT = 0;                                // fp32 running feature [n][c][p]
constexpr size_t OF_T    = OF_FEAT + SZ_NPC;                 // t   [n][p][c]
constexpr size_t OF_KH   = OF_T    + SZ_NPC;                 // kh  [n][p][c]   (aliased as fea later)
constexpr size_t OF_VV   = OF_KH   + SZ_NPC;                 // vv  [n][p][c]   (aliased as f2a later)
constexpr size_t OF_AO   = OF_VV   + SZ_NPC;                 // attn out [n][p][c]
constexpr size_t OF_QH   = OF_AO   + SZ_NPC;                 // qh [s][n][c]
constexpr size_t OF_HNW  = OF_QH   + (size_t)SEQL*NB*CD;     // hnW [r][n][o]
constexpr size_t OF_SCV  = OF_HNW  + (size_t)9*NB*CD;        // sconv [p][o]
constexpr size_t OF_WRG  = OF_SCV  + (size_t)PP*CD;          // W_region [r][o][c]
constexpr size_t OF_WCT  = OF_WRG  + (size_t)9*CD*HND;       // conv wT [c][tap][o] fp32
constexpr size_t OF_WKT  = OF_WCT  + (size_t)CD*9*CD;        // Wk^T [c][o]
constexpr size_t OF_WVT  = OF_WKT  + (size_t)CD*CD;
constexpr size_t OF_WOT  = OF_WVT  + (size_t)CD*CD;
constexpr size_t OF_W1T  = OF_WOT  + (size_t)CD*CD;
constexpr size_t OF_W2T  = OF_W1T  + (size_t)CD*CD;
constexpr size_t OF_FLAG = OF_W2T  + (size_t)CD*CD;          // dtype flag (int)
// end ~= 89.5 MiB

DEV float bf2f(bf16 v) { return __bfloat162float(v); }

// dtype-adaptive input load: bf=1 -> bf16 storage, bf=0 -> fp32 storage
DEV float LD(const void* p, size_t i, int bf) {
  return bf ? __bfloat162float(((const bf16*)p)[i]) : ((const float*)p)[i];
}
DEV int get_bf(const float* ws) { return ((const int*)ws)[OF_FLAG]; }

// detect storage dtype from mnorm_g (== all ones): fp32 1.0 -> 0x3F800000 (low16==0),
// bf16 pair (1.0,1.0) -> 0x3F803F80 (low16!=0)
__global__ void k_detect(const void* g, float* ws) {
  if (threadIdx.x == 0 && blockIdx.x == 0) {
    unsigned w = *(const unsigned*)g;
    ((int*)ws)[OF_FLAG] = ((w & 0xFFFFu) != 0u) ? 1 : 0;
  }
}

// LayerNorm reduction helper: tile[o][x] with row stride `stride`, 256 threads.
// Produces red[512+x]=mean, red[544+x]=rstd for x in [0,32).
DEV void ln_reduce(const float* tile, int stride, float* red, int tid) {
  const int x = tid & 31, seg = tid >> 5;
  float s = 0.f, sq = 0.f;
  for (int i = 0; i < 32; ++i) {
    float v = tile[(seg*32 + i)*stride + x];
    s += v; sq += v*v;
  }
  red[seg*32 + x] = s;
  red[256 + seg*32 + x] = sq;
  __syncthreads();
  if (tid < 32) {
    float ts = 0.f, tq = 0.f;
    for (int g = 0; g < 8; ++g) { ts += red[g*32 + tid]; tq += red[256 + g*32 + tid]; }
    float m = ts * (1.f/CD);
    float var = tq * (1.f/CD) - m*m;
    red[512 + tid] = m;
    red[544 + tid] = 1.f / sqrtf(var + 1e-5f);
  }
  __syncthreads();
}

// Stage a 32-row x 256-col fp32 tile transposed into LDS [c][36]
DEV void stage36(const float* __restrict__ X, float* __restrict__ L, int tid) {
  const int r = tid >> 3;
#pragma unroll
  for (int i = 0; i < 8; ++i) {
    const int c4 = (tid & 7)*32 + i*4;
    float4 v = *(const float4*)&X[(size_t)r*CD + c4];
    L[(c4+0)*36 + r] = v.x; L[(c4+1)*36 + r] = v.y;
    L[(c4+2)*36 + r] = v.z; L[(c4+3)*36 + r] = v.w;
  }
}

// acc[r] += sum_c X[r][c] * Wt[c][o]
DEV void gemm36(const float* __restrict__ L, const float* __restrict__ Wt, int o, float acc[32]) {
  const float* wp = Wt + o;
  for (int c = 0; c < CD; ++c) {
    const float w = wp[(size_t)c*CD];
#pragma unroll
    for (int r4 = 0; r4 < 8; ++r4) {
      float4 v = *(const float4*)&L[c*36 + r4*4];
      acc[r4*4+0] += w*v.x; acc[r4*4+1] += w*v.y;
      acc[r4*4+2] += w*v.z; acc[r4*4+3] += w*v.w;
    }
  }
}

// ---------------- prep kernels ----------------

__global__ __launch_bounds__(256) void k_init(const void* __restrict__ f, float* __restrict__ ws) {
  const int bf = get_bf(ws);
  size_t i = (size_t)blockIdx.x*256 + threadIdx.x;
  ws[OF_FEAT + i] = LD(f, i, bf);
}

// q = relu(emb @ qconv_w^T + qb); qh = q @ Wq^T + bq     (one block per (s,n))
__global__ __launch_bounds__(256) void k_qh(const void* __restrict__ emb, const void* __restrict__ qw,
                                            const void* __restrict__ qb, const void* __restrict__ ipw,
                                            const void* __restrict__ ipb, float* __restrict__ ws) {
  const int bf = get_bf(ws);
  const int b = blockIdx.x, s = b / NB, n = b % NB;
  const int o = threadIdx.x;
  __shared__ float se[EMBD];
  __shared__ float sq[CD];
  for (int i = o; i < EMBD; i += CD) se[i] = LD(emb, ((size_t)n*SEQL + s)*EMBD + i, bf);
  __syncthreads();
  float a = LD(qb, o, bf);
  if (bf) {
    const bf16* wr = (const bf16*)qw + (size_t)o*EMBD;
    for (int c = 0; c < EMBD; ++c) a += se[c]*bf2f(wr[c]);
  } else {
    const float* wr = (const float*)qw + (size_t)o*EMBD;
    for (int c = 0; c < EMBD; ++c) a += se[c]*wr[c];
  }
  sq[o] = fmaxf(a, 0.f);
  __syncthreads();
  float a2 = LD(ipb, o, bf);
  if (bf) {
    const bf16* wq = (const bf16*)ipw + (size_t)o*CD;
    for (int c = 0; c < CD; ++c) a2 += sq[c]*bf2f(wq[c]);
  } else {
    const float* wq = (const float*)ipw + (size_t)o*CD;
    for (int c = 0; c < CD; ++c) a2 += sq[c]*wq[c];
  }
  ws[OF_QH + ((size_t)s*NB + n)*CD + o] = a2;
}

// Tap-sums of hn-channel conv weights per border pattern r = ry*3+rx
__global__ __launch_bounds__(256) void k_wregion(const void* __restrict__ mw, float* __restrict__ ws) {
  const int bf = get_bf(ws);
  const int gid = blockIdx.x*256 + threadIdx.x;
  const int c = gid & (HND-1);
  const int o = (gid >> 9) & (CD-1);
  const int r = gid >> 17;
  const int ry = r/3, rx = r%3;
  float s = 0.f;
  for (int dy = 0; dy < 3; ++dy) {
    if (ry == 0 && dy == 0) continue;
    if (ry == 2 && dy == 2) continue;
    for (int dx = 0; dx < 3; ++dx) {
      if (rx == 0 && dx == 0) continue;
      if (rx == 2 && dx == 2) continue;
      s += LD(mw, ((size_t)o*CIN + 264 + c)*9 + dy*3 + dx, bf);
    }
  }
  ws[OF_WRG + gid] = s;
}

// hnW[r][n][o] = hn[n] . W_region[r][o][:]
__global__ __launch_bounds__(256) void k_hnw(const void* __restrict__ hn, float* __restrict__ ws) {
  const int bf = get_bf(ws);
  const int b = blockIdx.x, r = b / NB, n = b % NB;
  const int o = threadIdx.x;
  __shared__ float sh[HND];
  for (int i = o; i < HND; i += CD) sh[i] = LD(hn, (size_t)n*HND + i, bf);
  __syncthreads();
  const float* wr = ws + OF_WRG + ((size_t)r*CD + o)*HND;
  float a = 0.f;
  for (int c = 0; c < HND; ++c) a += sh[c]*wr[c];
  ws[OF_HNW + ((size_t)r*NB + n)*CD + o] = a;
}

DEV float spat(int c, int yy, int xx) {
  switch (c) {
    case 0: return xx*(1.f/16) - 1.f;
    case 1: return yy*(1.f/16) - 1.f;
    case 2: return (xx+1)*(1.f/16) - 1.f;
    case 3: return (yy+1)*(1.f/16) - 1.f;
    case 4: return (xx+0.5f)*(1.f/16) - 1.f;
    case 5: return (yy+0.5f)*(1.f/16) - 1.f;
    default: return 1.f/32;
  }
}

// sconv[p][o] = conv contribution of the 8 spatial channels (batch-invariant)
__global__ __launch_bounds__(256) void k_sconv(const void* __restrict__ mw, float* __restrict__ ws) {
  const int bf = get_bf(ws);
  const int p = blockIdx.x, o = threadIdx.x;
  const int y = p >> 5, x = p & 31;
  float a = 0.f;
  for (int c = 0; c < 8; ++c)
    for (int dy = 0; dy < 3; ++dy) {
      int yy = y + dy - 1; if ((unsigned)yy >= 32u) continue;
      for (int dx = 0; dx < 3; ++dx) {
        int xx = x + dx - 1; if ((unsigned)xx >= 32u) continue;
        a += LD(mw, ((size_t)o*CIN + 256 + c)*9 + dy*3 + dx, bf) * spat(c, yy, xx);
      }
    }
  ws[OF_SCV + (size_t)p*CD + o] = a;
}

// conv weights (feat channels) transposed fp32: wt[c][tap][o]
__global__ __launch_bounds__(256) void k_wconvT(const void* __restrict__ mw, float* __restrict__ ws) {
  const int bf = get_bf(ws);
  const int b = blockIdx.x, c = b / 9, tap = b % 9;
  const int o = threadIdx.x;
  ws[OF_WCT + ((size_t)c*9 + tap)*CD + o] = LD(mw, ((size_t)o*CIN + c)*9 + tap, bf);
}

// GEMM weights transposed fp32: [c][o]
__global__ __launch_bounds__(256) void k_wT(const void* __restrict__ ipw, const void* __restrict__ opw,
                                            const void* __restrict__ l1w, const void* __restrict__ l2w,
                                            float* __restrict__ ws) {
  const int bf = get_bf(ws);
  const int b = blockIdx.x, which = b / CD, c = b % CD;
  const int o = threadIdx.x;
  float v; size_t dst;
  switch (which) {
    case 0: v = LD(ipw, ((size_t)(256 + o))*CD + c, bf); dst = OF_WKT; break;
    case 1: v = LD(ipw, ((size_t)(512 + o))*CD + c, bf); dst = OF_WVT; break;
    case 2: v = LD(opw, (size_t)o*CD + c, bf);           dst = OF_WOT; break;
    case 3: v = LD(l1w, (size_t)o*CD + c, bf);           dst = OF_W1T; break;
    default: v = LD(l2w, (size_t)o*CD + c, bf);          dst = OF_W2T; break;
  }
  ws[dst + (size_t)c*CD + o] = v;
}

// ---------------- per-step kernels ----------------

#define CONV_UPD(VV, XI) do {                                  \
    const float vv_ = (VV);                                    \
    if ((XI) >= 1)  acc[(XI)-1] += w[dy*3+2]*vv_;              \
    acc[(XI)]       += w[dy*3+1]*vv_;                          \
    if ((XI) <= 30) acc[(XI)+1] += w[dy*3+0]*vv_;              \
  } while (0)

// 3x3 conv over feat channels + static contributions + relu + LayerNorm -> t[n][p][c]
__global__ __launch_bounds__(256) void k_conv_ln(const void* __restrict__ mg, const void* __restrict__ mbv,
                                                 float* __restrict__ ws) {
  __shared__ float smem[8448 + 576];
  const int bfv = get_bf(ws);
  const int b = blockIdx.x, n = b >> 5, y = b & 31;
  const int tid = threadIdx.x, o = tid;

  float acc[32];
  {
    const int ry = (y == 0) ? 0 : ((y == 31) ? 2 : 1);
    const float* hnw = ws + OF_HNW;
    const float bl = hnw[((size_t)(ry*3+0)*NB + n)*CD + o];
    const float bm = hnw[((size_t)(ry*3+1)*NB + n)*CD + o];
    const float br = hnw[((size_t)(ry*3+2)*NB + n)*CD + o];
    const float* sc = ws + OF_SCV + (size_t)(y*32)*CD + o;
#pragma unroll
    for (int x = 0; x < 32; ++x)
      acc[x] = sc[(size_t)x*CD] + (x == 0 ? bl : (x == 31 ? br : bm));
  }

  const float* feat = ws + OF_FEAT + (size_t)n*CD*PP;
  float* Ls = smem;

  for (int c0 = 0; c0 < CD; c0 += 64) {
    __syncthreads();
#pragma unroll
    for (int i = 0; i < 6; ++i) {
      const int row = i*32 + (tid >> 3);       // 0..191 = cl*3 + dyi
      const int cl = row / 3;
      const int dyi = row - cl*3;
      const int yy = y + dyi - 1;
      const int xx = (tid & 7)*4;
      float4 v = make_float4(0.f, 0.f, 0.f, 0.f);
      if ((unsigned)yy < 32u)
        v = *(const float4*)&feat[((size_t)(c0 + cl)*32 + yy)*32 + xx];
      *(float4*)&Ls[row*32 + xx] = v;
    }
    __syncthreads();
    const float* wt = ws + OF_WCT + (size_t)c0*9*CD + o;
#pragma unroll 1
    for (int cl = 0; cl < 64; ++cl) {
      float w[9];
#pragma unroll
      for (int t9 = 0; t9 < 9; ++t9) w[t9] = wt[(size_t)(cl*9 + t9)*CD];
#pragma unroll
      for (int dy = 0; dy < 3; ++dy) {
        const float* Lr = &Ls[(cl*3 + dy)*32];
#pragma unroll
        for (int x4 = 0; x4 < 8; ++x4) {
          float4 v = *(const float4*)&Lr[x4*4];
          CONV_UPD(v.x, x4*4 + 0);
          CONV_UPD(v.y, x4*4 + 1);
          CONV_UPD(v.z, x4*4 + 2);
          CONV_UPD(v.w, x4*4 + 3);
        }
      }
    }
  }
  __syncthreads();
  float* tile = smem;
  float* red = smem + 8448;
#pragma unroll
  for (int x = 0; x < 32; ++x) tile[o*33 + x] = fmaxf(acc[x], 0.f);
  __syncthreads();
  ln_reduce(tile, 33, red, tid);
  const float g = LD(mg, o, bfv), bb = LD(mbv, o, bfv);
  float* tp = ws + OF_T + ((size_t)n*PP + (size_t)y*32)*CD + o;
#pragma unroll
  for (int x = 0; x < 32; ++x)
    tp[(size_t)x*CD] = (tile[o*33 + x] - red[512 + x]) * red[544 + x] * g + bb;
}

// fused K and V projections
__global__ __launch_bounds__(256) void k_kv(const void* __restrict__ ipb, float* __restrict__ ws) {
  __shared__ float smem[9216];
  const int bf = get_bf(ws);
  const int b = blockIdx.x, n = b >> 5, p0 = (b & 31) << 5;
  const int tid = threadIdx.x, o = tid;
  stage36(ws + OF_T + ((size_t)n*PP + p0)*CD, smem, tid);
  __syncthreads();
  float ak[32], av[32];
#pragma unroll
  for (int r = 0; r < 32; ++r) { ak[r] = 0.f; av[r] = 0.f; }
  const float* wk = ws + OF_WKT + o;
  const float* wv = ws + OF_WVT + o;
  for (int c = 0; c < CD; ++c) {
    const float wkc = wk[(size_t)c*CD];
    const float wvc = wv[(size_t)c*CD];
#pragma unroll
    for (int r4 = 0; r4 < 8; ++r4) {
      float4 v = *(const float4*)&smem[c*36 + r4*4];
      ak[r4*4+0] += wkc*v.x; ak[r4*4+1] += wkc*v.y; ak[r4*4+2] += wkc*v.z; ak[r4*4+3] += wkc*v.w;
      av[r4*4+0] += wvc*v.x; av[r4*4+1] += wvc*v.y; av[r4*4+2] += wvc*v.z; av[r4*4+3] += wvc*v.w;
    }
  }
  const float bk = LD(ipb, 256 + o, bf), bv = LD(ipb, 512 + o, bf);
  float* KH = ws + OF_KH + ((size_t)n*PP + p0)*CD + o;
  float* VV = ws + OF_VV + ((size_t)n*PP + p0)*CD + o;
#pragma unroll
  for (int r = 0; r < 32; ++r) { KH[(size_t)r*CD] = ak[r] + bk; VV[(size_t)r*CD] = av[r] + bv; }
}

// cross-batch attention: one wave per (p, h)
__global__ __launch_bounds__(64) void k_attn(int s, float* __restrict__ ws) {
  __shared__ float SQ[16*132], SK[16*132], SV[16*132], SA[16*20];
  const int p = blockIdx.x >> 1, h = blockIdx.x & 1;
  const int lane = threadIdx.x;
  for (int i = lane; i < 16*128; i += 64) {
    const int l = i >> 7, d = i & 127;
    SQ[l*132 + d] = ws[OF_QH + ((size_t)(s*NB + l))*CD + h*128 + d];
    SK[l*132 + d] = ws[OF_KH + ((size_t)l*PP + p)*CD + h*128 + d];
    SV[l*132 + d] = ws[OF_VV + ((size_t)l*PP + p)*CD + h*128 + d];
  }
  __syncthreads();
  const int l = lane >> 2, mg = lane & 3;
  float sc[4];
#pragma unroll
  for (int j = 0; j < 4; ++j) {
    const int m = mg*4 + j;
    float a = 0.f;
    for (int d4 = 0; d4 < 128; d4 += 4) {
      float4 q = *(const float4*)&SQ[l*132 + d4];
      float4 k = *(const float4*)&SK[m*132 + d4];
      a += q.x*k.x + q.y*k.y + q.z*k.z + q.w*k.w;
    }
    sc[j] = a * 0.08838834764831845f;   // 1/sqrt(128)
  }
  float mx = fmaxf(fmaxf(sc[0], sc[1]), fmaxf(sc[2], sc[3]));
  mx = fmaxf(mx, __shfl_xor(mx, 1, 64));
  mx = fmaxf(mx, __shfl_xor(mx, 2, 64));
  float sum = 0.f;
#pragma unroll
  for (int j = 0; j < 4; ++j) { sc[j] = __expf(sc[j] - mx); sum += sc[j]; }
  sum += __shfl_xor(sum, 1, 64);
  sum += __shfl_xor(sum, 2, 64);
  const float inv = 1.f / sum;
#pragma unroll
  for (int j = 0; j < 4; ++j) SA[l*20 + mg*4 + j] = sc[j]*inv;
  __syncthreads();
  float oa[32];
#pragma unroll
  for (int d = 0; d < 32; ++d) oa[d] = 0.f;
  for (int m = 0; m < 16; ++m) {
    const float a = SA[l*20 + m];
#pragma unroll
    for (int d4 = 0; d4 < 8; ++d4) {
      float4 v = *(const float4*)&SV[m*132 + mg*32 + d4*4];
      oa[d4*4+0] += a*v.x; oa[d4*4+1] += a*v.y; oa[d4*4+2] += a*v.z; oa[d4*4+3] += a*v.w;
    }
  }
  float* dst = ws + OF_AO + ((size_t)l*PP + p)*CD + h*128 + mg*32;
#pragma unroll
  for (int d4 = 0; d4 < 8; ++d4)
    *(float4*)&dst[d4*4] = make_float4(oa[d4*4], oa[d4*4+1], oa[d4*4+2], oa[d4*4+3]);
}

// fea = LN(t + attn_o @ out_proj^T + b)   -> OF_KH (aliased)
__global__ __launch_bounds__(256) void k_outproj_ln(const void* __restrict__ opb, const void* __restrict__ ng,
                                                    const void* __restrict__ nbv, float* __restrict__ ws) {
  __shared__ float smem[9216 + 576];
  const int bf = get_bf(ws);
  const int b = blockIdx.x, n = b >> 5, p0 = (b & 31) << 5;
  const int tid = threadIdx.x, o = tid;
  stage36(ws + OF_AO + ((size_t)n*PP + p0)*CD, smem, tid);
  __syncthreads();
  float acc[32];
#pragma unroll
  for (int r = 0; r < 32; ++r) acc[r] = 0.f;
  gemm36(smem, ws + OF_WOT, o, acc);
  const float bo = LD(opb, o, bf);
  const float* tr = ws + OF_T + ((size_t)n*PP + p0)*CD + o;
#pragma unroll
  for (int r = 0; r < 32; ++r) acc[r] += bo + tr[(size_t)r*CD];
  __syncthreads();
#pragma unroll
  for (int r = 0; r < 32; ++r) smem[o*36 + r] = acc[r];
  __syncthreads();
  float* red = smem + 9216;
  ln_reduce(smem, 36, red, tid);
  const float g = LD(ng, o, bf), bb = LD(nbv, o, bf);
  float* fea = ws + OF_KH + ((size_t)n*PP + p0)*CD + o;
#pragma unroll
  for (int r = 0; r < 32; ++r)
    fea[(size_t)r*CD] = (smem[o*36 + r] - red[512 + r]) * red[544 + r] * g + bb;
}

// f2a = relu(fea @ lin1^T + b)  -> OF_VV (aliased)
__global__ __launch_bounds__(256) void k_lin1(const void* __restrict__ l1b, float* __restrict__ ws) {
  __shared__ float smem[9216];
  const int bf = get_bf(ws);
  const int b = blockIdx.x, n = b >> 5, p0 = (b & 31) << 5;
  const int tid = threadIdx.x, o = tid;
  stage36(ws + OF_KH + ((size_t)n*PP + p0)*CD, smem, tid);
  __syncthreads();
  float acc[32];
#pragma unroll
  for (int r = 0; r < 32; ++r) acc[r] = 0.f;
  gemm36(smem, ws + OF_W1T, o, acc);
  const float bb = LD(l1b, o, bf);
  float* dst = ws + OF_VV + ((size_t)n*PP + p0)*CD + o;
#pragma unroll
  for (int r = 0; r < 32; ++r) dst[(size_t)r*CD] = fmaxf(acc[r] + bb, 0.f);
}

// fea2 = LN(fea + f2a @ lin2^T + b); if active: feat[n][o][p] = fea2
__global__ __launch_bounds__(256) void k_lin2(const void* __restrict__ l2b, const void* __restrict__ nfg,
                                              const void* __restrict__ nfb, const int* __restrict__ words,
                                              int s, float* __restrict__ ws) {
  __shared__ float smem[9216 + 576];
  const int bf = get_bf(ws);
  const int b = blockIdx.x, n = b >> 5, p0 = (b & 31) << 5;
  const int tid = threadIdx.x, o = tid;
  stage36(ws + OF_VV + ((size_t)n*PP + p0)*CD, smem, tid);
  __syncthreads();
  float acc[32];
#pragma unroll
  for (int r = 0; r < 32; ++r) acc[r] = 0.f;
  gemm36(smem, ws + OF_W2T, o, acc);
  const float bb = LD(l2b, o, bf);
  const float* fer = ws + OF_KH + ((size_t)n*PP + p0)*CD + o;
#pragma unroll
  for (int r = 0; r < 32; ++r) acc[r] += bb + fer[(size_t)r*CD];
  __syncthreads();
#pragma unroll
  for (int r = 0; r < 32; ++r) smem[o*36 + r] = acc[r];
  __syncthreads();
  float* red = smem + 9216;
  ln_reduce(smem, 36, red, tid);
  const float g = LD(nfg, o, bf), b2 = LD(nfb, o, bf);
#pragma unroll
  for (int r = 0; r < 32; ++r)
    smem[o*36 + r] = (smem[o*36 + r] - red[512 + r]) * red[544 + r] * g + b2;
  __syncthreads();
  if (words[s] != 0) {
    const int r = tid & 31, og = tid >> 5;
#pragma unroll 1
    for (int it = 0; it < 32; ++it) {
      const int oo = og + it*8;
      ws[OF_FEAT + ((size_t)n*CD + oo)*PP + p0 + r] = smem[oo*36 + r];
    }
  }
}

__global__ __launch_bounds__(256) void k_final(const float* __restrict__ ws, void* __restrict__ out) {
  const int bf = get_bf(ws);
  size_t i = (size_t)blockIdx.x*256 + threadIdx.x;
  float v = ws[OF_FEAT + i];
  if (bf) ((bf16*)out)[i] = __float2bfloat16(v);
  else    ((float*)out)[i] = v;
}

extern "C" void kernel_launch(void* const* d_in, const int* in_sizes, int n_in,
                              void* d_out, int out_size, void* d_ws, size_t ws_size,
                              hipStream_t stream) {
  (void)in_sizes; (void)n_in; (void)out_size; (void)ws_size;
  const void* hn      = d_in[1];
  const void* feature = d_in[2];
  const void* emb     = d_in[3];
  const int*  words   = (const int*)d_in[4];
  const void* qw  = d_in[5];
  const void* qb  = d_in[6];
  const void* mw  = d_in[7];
  const void* mg  = d_in[8];
  const void* mb  = d_in[9];
  const void* ipw = d_in[10];
  const void* ipb = d_in[11];
  const void* opw = d_in[12];
  const void* opb = d_in[13];
  const void* ng  = d_in[14];
  const void* nb  = d_in[15];
  const void* l1w = d_in[16];
  const void* l1b = d_in[17];
  const void* l2w = d_in[18];
  const void* l2b = d_in[19];
  const void* nfg = d_in[20];
  const void* nfb = d_in[21];
  float* ws = (float*)d_ws;

  k_detect<<<1, 64, 0, stream>>>(mg, ws);
  k_init<<<16384, 256, 0, stream>>>(feature, ws);
  k_qh<<<SEQL*NB, 256, 0, stream>>>(emb, qw, qb, ipw, ipb, ws);
  k_wregion<<<(9*CD*HND)/256, 256, 0, stream>>>(mw, ws);
  k_hnw<<<9*NB, 256, 0, stream>>>(hn, ws);
  k_sconv<<<PP, 256, 0, stream>>>(mw, ws);
  k_wconvT<<<CD*9, 256, 0, stream>>>(mw, ws);
  k_wT<<<5*CD, 256, 0, stream>>>(ipw, opw, l1w, l2w, ws);

  for (int s = 0; s < SEQL; ++s) {
    k_conv_ln<<<NB*32, 256, 0, stream>>>(mg, mb, ws);
    k_kv<<<NB*32, 256, 0, stream>>>(ipb, ws);
    k_attn<<<PP*2, 64, 0, stream>>>(s, ws);
    k_outproj_ln<<<NB*32, 256, 0, stream>>>(opb, ng, nb, ws);
    k_lin1<<<NB*32, 256, 0, stream>>>(l1b, ws);
    k_lin2<<<NB*32, 256, 0, stream>>>(l2b, nfg, nfb, words, s, ws);
  }
  k_final<<<16384, 256, 0, stream>>>(ws, (void*)d_out);
}

// Round 3
// 6146.705 us; speedup vs baseline: 1.9706x; 1.9706x over previous
//
#include <hip/hip_runtime.h>
#include <hip/hip_bf16.h>
#include <cstddef>

typedef __hip_bfloat16 bf16;
typedef short short8 __attribute__((ext_vector_type(8)));
typedef float float4v __attribute__((ext_vector_type(4)));
#define DEV static __device__ __forceinline__

constexpr int NB = 16;     // batch
constexpr int SEQL = 20;
constexpr int CD = 256;    // VD
constexpr int PP = 1024;   // 32*32
constexpr int HND = 512;
constexpr int EMBD = 300;
constexpr int CIN = 776;   // 256 + 8 + 512

// ---- workspace layout (float element offsets) ----
constexpr size_t SZ_NPC = (size_t)NB * PP * CD;              // 4,194,304
constexpr size_t OF_FEATB = 0;                               // bf16 running feature [n][p][c] (2M floats = 4M bf16)
constexpr size_t OF_T    = OF_FEATB + SZ_NPC/2;              // t   [n][p][c] fp32
constexpr size_t OF_KH   = OF_T    + SZ_NPC;                 // kh  [n][p][c]   (aliased as fea later)
constexpr size_t OF_VV   = OF_KH   + SZ_NPC;                 // vv  [n][p][c]   (aliased as f2a later)
constexpr size_t OF_AO   = OF_VV   + SZ_NPC;                 // attn out [n][p][c]
constexpr size_t OF_QH   = OF_AO   + SZ_NPC;                 // qh [s][n][c]
constexpr size_t OF_HNW  = OF_QH   + (size_t)SEQL*NB*CD;     // hnW [r][n][o]
constexpr size_t OF_SCV  = OF_HNW  + (size_t)9*NB*CD;        // sconv [p][o]
constexpr size_t OF_WRG  = OF_SCV  + (size_t)PP*CD;          // W_region [r][o][c]
constexpr size_t OF_AW   = OF_WRG  + (size_t)9*CD*HND;       // conv W packed A-frags (589,824 bf16 = 294,912 floats)
constexpr size_t OF_WKT  = OF_AW   + (size_t)294912;         // Wk^T [c][o] fp32
constexpr size_t OF_WVT  = OF_WKT  + (size_t)CD*CD;
constexpr size_t OF_WOT  = OF_WVT  + (size_t)CD*CD;
constexpr size_t OF_W1T  = OF_WOT  + (size_t)CD*CD;
constexpr size_t OF_W2T  = OF_W1T  + (size_t)CD*CD;
constexpr size_t OF_FLAG = OF_W2T  + (size_t)CD*CD;          // dtype flag (int)
// end ~= 84.2 MB

DEV float bf2f(bf16 v) { return __bfloat162float(v); }
DEV bf16 f2bf(float v) { return __float2bfloat16(v); }

// dtype-adaptive input load: bf=1 -> bf16 storage, bf=0 -> fp32 storage
DEV float LD(const void* p, size_t i, int bf) {
  return bf ? __bfloat162float(((const bf16*)p)[i]) : ((const float*)p)[i];
}
DEV int get_bf(const float* ws) { return ((const int*)ws)[OF_FLAG]; }

__global__ void k_detect(const void* g, float* ws) {
  if (threadIdx.x == 0 && blockIdx.x == 0) {
    unsigned w = *(const unsigned*)g;
    ((int*)ws)[OF_FLAG] = ((w & 0xFFFFu) != 0u) ? 1 : 0;
  }
}

// LayerNorm reduction helper: tile[o][x] stride `stride`, 256 threads.
// Produces red[512+x]=mean, red[544+x]=rstd for x in [0,32).
DEV void ln_reduce(const float* tile, int stride, float* red, int tid) {
  const int x = tid & 31, seg = tid >> 5;
  float s = 0.f, sq = 0.f;
  for (int i = 0; i < 32; ++i) {
    float v = tile[(seg*32 + i)*stride + x];
    s += v; sq += v*v;
  }
  red[seg*32 + x] = s;
  red[256 + seg*32 + x] = sq;
  __syncthreads();
  if (tid < 32) {
    float ts = 0.f, tq = 0.f;
    for (int g = 0; g < 8; ++g) { ts += red[g*32 + tid]; tq += red[256 + g*32 + tid]; }
    float m = ts * (1.f/CD);
    float var = tq * (1.f/CD) - m*m;
    red[512 + tid] = m;
    red[544 + tid] = 1.f / sqrtf(var + 1e-5f);
  }
  __syncthreads();
}

// Stage a 32-row x 256-col fp32 tile transposed into LDS [c][36]
DEV void stage36(const float* __restrict__ X, float* __restrict__ L, int tid) {
  const int r = tid >> 3;
#pragma unroll
  for (int i = 0; i < 8; ++i) {
    const int c4 = (tid & 7)*32 + i*4;
    float4 v = *(const float4*)&X[(size_t)r*CD + c4];
    L[(c4+0)*36 + r] = v.x; L[(c4+1)*36 + r] = v.y;
    L[(c4+2)*36 + r] = v.z; L[(c4+3)*36 + r] = v.w;
  }
}

// acc[r] += sum_c X[r][c] * Wt[c][o]
DEV void gemm36(const float* __restrict__ L, const float* __restrict__ Wt, int o, float acc[32]) {
  const float* wp = Wt + o;
  for (int c = 0; c < CD; ++c) {
    const float w = wp[(size_t)c*CD];
#pragma unroll
    for (int r4 = 0; r4 < 8; ++r4) {
      float4 v = *(const float4*)&L[c*36 + r4*4];
      acc[r4*4+0] += w*v.x; acc[r4*4+1] += w*v.y;
      acc[r4*4+2] += w*v.z; acc[r4*4+3] += w*v.w;
    }
  }
}

// ---------------- prep kernels ----------------

// transpose input feature [n][c][p] -> bf16 [n][p][c]
__global__ __launch_bounds__(256) void k_init(const void* __restrict__ f, float* __restrict__ ws) {
  const int bf = get_bf(ws);
  const int b = blockIdx.x;            // (n,p): 16*1024 blocks
  const int n = b >> 10, p = b & 1023;
  const int c = threadIdx.x;
  bf16* fb = (bf16*)(ws + OF_FEATB);
  fb[(size_t)b*CD + c] = f2bf(LD(f, ((size_t)n*CD + c)*PP + p, bf));
}

// q = relu(emb @ qconv_w^T + qb); qh = q @ Wq^T + bq     (one block per (s,n))
__global__ __launch_bounds__(256) void k_qh(const void* __restrict__ emb, const void* __restrict__ qw,
                                            const void* __restrict__ qb, const void* __restrict__ ipw,
                                            const void* __restrict__ ipb, float* __restrict__ ws) {
  const int bf = get_bf(ws);
  const int b = blockIdx.x, s = b / NB, n = b % NB;
  const int o = threadIdx.x;
  __shared__ float se[EMBD];
  __shared__ float sq[CD];
  for (int i = o; i < EMBD; i += CD) se[i] = LD(emb, ((size_t)n*SEQL + s)*EMBD + i, bf);
  __syncthreads();
  float a = LD(qb, o, bf);
  if (bf) {
    const bf16* wr = (const bf16*)qw + (size_t)o*EMBD;
    for (int c = 0; c < EMBD; ++c) a += se[c]*bf2f(wr[c]);
  } else {
    const float* wr = (const float*)qw + (size_t)o*EMBD;
    for (int c = 0; c < EMBD; ++c) a += se[c]*wr[c];
  }
  sq[o] = fmaxf(a, 0.f);
  __syncthreads();
  float a2 = LD(ipb, o, bf);
  if (bf) {
    const bf16* wq = (const bf16*)ipw + (size_t)o*CD;
    for (int c = 0; c < CD; ++c) a2 += sq[c]*bf2f(wq[c]);
  } else {
    const float* wq = (const float*)ipw + (size_t)o*CD;
    for (int c = 0; c < CD; ++c) a2 += sq[c]*wq[c];
  }
  ws[OF_QH + ((size_t)s*NB + n)*CD + o] = a2;
}

// Tap-sums of hn-channel conv weights per border pattern r = ry*3+rx
__global__ __launch_bounds__(256) void k_wregion(const void* __restrict__ mw, float* __restrict__ ws) {
  const int bf = get_bf(ws);
  const int gid = blockIdx.x*256 + threadIdx.x;
  const int c = gid & (HND-1);
  const int o = (gid >> 9) & (CD-1);
  const int r = gid >> 17;
  const int ry = r/3, rx = r%3;
  float s = 0.f;
  for (int dy = 0; dy < 3; ++dy) {
    if (ry == 0 && dy == 0) continue;
    if (ry == 2 && dy == 2) continue;
    for (int dx = 0; dx < 3; ++dx) {
      if (rx == 0 && dx == 0) continue;
      if (rx == 2 && dx == 2) continue;
      s += LD(mw, ((size_t)o*CIN + 264 + c)*9 + dy*3 + dx, bf);
    }
  }
  ws[OF_WRG + gid] = s;
}

// hnW[r][n][o] = hn[n] . W_region[r][o][:]
__global__ __launch_bounds__(256) void k_hnw(const void* __restrict__ hn, float* __restrict__ ws) {
  const int bf = get_bf(ws);
  const int b = blockIdx.x, r = b / NB, n = b % NB;
  const int o = threadIdx.x;
  __shared__ float sh[HND];
  for (int i = o; i < HND; i += CD) sh[i] = LD(hn, (size_t)n*HND + i, bf);
  __syncthreads();
  const float* wr = ws + OF_WRG + ((size_t)r*CD + o)*HND;
  float a = 0.f;
  for (int c = 0; c < HND; ++c) a += sh[c]*wr[c];
  ws[OF_HNW + ((size_t)r*NB + n)*CD + o] = a;
}

DEV float spat(int c, int yy, int xx) {
  switch (c) {
    case 0: return xx*(1.f/16) - 1.f;
    case 1: return yy*(1.f/16) - 1.f;
    case 2: return (xx+1)*(1.f/16) - 1.f;
    case 3: return (yy+1)*(1.f/16) - 1.f;
    case 4: return (xx+0.5f)*(1.f/16) - 1.f;
    case 5: return (yy+0.5f)*(1.f/16) - 1.f;
    default: return 1.f/32;
  }
}

// sconv[p][o] = conv contribution of the 8 spatial channels (batch-invariant)
__global__ __launch_bounds__(256) void k_sconv(const void* __restrict__ mw, float* __restrict__ ws) {
  const int bf = get_bf(ws);
  const int p = blockIdx.x, o = threadIdx.x;
  const int y = p >> 5, x = p & 31;
  float a = 0.f;
  for (int c = 0; c < 8; ++c)
    for (int dy = 0; dy < 3; ++dy) {
      int yy = y + dy - 1; if ((unsigned)yy >= 32u) continue;
      for (int dx = 0; dx < 3; ++dx) {
        int xx = x + dx - 1; if ((unsigned)xx >= 32u) continue;
        a += LD(mw, ((size_t)o*CIN + 256 + c)*9 + dy*3 + dx, bf) * spat(c, yy, xx);
      }
    }
  ws[OF_SCV + (size_t)p*CD + o] = a;
}

// pack conv feat-channel weights into MFMA A-frag order (bf16):
// AW[tap][chunk][mt][lane][j]  <-  W[o = mt*16 + (lane&15)][c = chunk*32 + (lane>>4)*8 + j][tap]
__global__ __launch_bounds__(256) void k_wpack(const void* __restrict__ mw, float* __restrict__ ws) {
  const int bf = get_bf(ws);
  const int idx = blockIdx.x*256 + threadIdx.x;       // 589,824 total
  const int j = idx & 7;
  const int lane = (idx >> 3) & 63;
  const int mt = (idx >> 9) & 15;
  const int ch = (idx >> 13) & 7;
  const int tap = idx >> 16;
  const int o = mt*16 + (lane & 15);
  const int c = ch*32 + (lane >> 4)*8 + j;
  bf16* aw = (bf16*)(ws + OF_AW);
  aw[idx] = f2bf(LD(mw, ((size_t)o*CIN + c)*9 + tap, bf));
}

// GEMM weights transposed fp32: [c][o]
__global__ __launch_bounds__(256) void k_wT(const void* __restrict__ ipw, const void* __restrict__ opw,
                                            const void* __restrict__ l1w, const void* __restrict__ l2w,
                                            float* __restrict__ ws) {
  const int bf = get_bf(ws);
  const int b = blockIdx.x, which = b / CD, c = b % CD;
  const int o = threadIdx.x;
  float v; size_t dst;
  switch (which) {
    case 0: v = LD(ipw, ((size_t)(256 + o))*CD + c, bf); dst = OF_WKT; break;
    case 1: v = LD(ipw, ((size_t)(512 + o))*CD + c, bf); dst = OF_WVT; break;
    case 2: v = LD(opw, (size_t)o*CD + c, bf);           dst = OF_WOT; break;
    case 3: v = LD(l1w, (size_t)o*CD + c, bf);           dst = OF_W1T; break;
    default: v = LD(l2w, (size_t)o*CD + c, bf);          dst = OF_W2T; break;
  }
  ws[dst + (size_t)c*CD + o] = v;
}

// ---------------- per-step kernels ----------------

// 3x3 conv via bf16 MFMA implicit GEMM + static contributions + relu + LN -> t[n][p][c]
// block = (n, y): 256 thr = 4 waves; wave w: o-tiles w*4..w*4+3; n-tiles x:0..15 / 16..31
__global__ __launch_bounds__(256) void k_conv_mfma(const void* __restrict__ mg, const void* __restrict__ mbv,
                                                   float* __restrict__ ws) {
  __shared__ float smem[13464];            // X3T[3][34][264] bf16 = 53,856B; reused as tile[256][33]+red
  bf16* Xs = (bf16*)smem;
  const int bfv = get_bf(ws);
  const int b = blockIdx.x, n = b >> 5, y = b & 31;
  const int tid = threadIdx.x;
  const int w = tid >> 6, lane = tid & 63;
  const bf16* fb = (const bf16*)(ws + OF_FEATB);

  // ---- stage rows y-1..y+1 (zero-padded) transposed: X3T[r][1+x][c], c-stride 264 ----
  const short8 zero8 = {0,0,0,0,0,0,0,0};
  if (tid < 192) {   // x-pad columns xp=0 and xp=33
    const int r = tid >> 6, xp = ((tid >> 5) & 1) * 33, c0 = (tid & 31)*8;
    *(short8*)&Xs[(r*34 + xp)*264 + c0] = zero8;
  }
#pragma unroll
  for (int u = 0; u < 12; ++u) {
    const int lin = u*256 + tid;
    const int cgrp = lin & 31, xl = (lin >> 5) & 31, r = lin >> 10;
    const int row = y + r - 1;
    short8 v = zero8;
    if ((unsigned)row < 32u)
      v = *(const short8*)&fb[((size_t)(n*PP + row*32 + xl))*CD + cgrp*8];
    *(short8*)&Xs[(r*34 + 1 + xl)*264 + cgrp*8] = v;
  }
  __syncthreads();

  // ---- MFMA K-loop: 9 taps x 8 chunks ----
  float4v acc[4][2];
#pragma unroll
  for (int mti = 0; mti < 4; ++mti) { acc[mti][0] = (float4v)0.f; acc[mti][1] = (float4v)0.f; }
  const bf16* AW = (const bf16*)(ws + OF_AW);
  const int xb = lane & 15, quad = lane >> 4;
#pragma unroll 1
  for (int tap = 0; tap < 9; ++tap) {
    const int dy = tap/3, dx = tap - dy*3;
#pragma unroll 1
    for (int ch = 0; ch < 8; ++ch) {
      short8 b0 = *(const short8*)&Xs[(dy*34 + xb + dx)*264 + ch*32 + quad*8];
      short8 b1 = *(const short8*)&Xs[(dy*34 + xb + 16 + dx)*264 + ch*32 + quad*8];
      const bf16* ap = AW + (((size_t)(tap*8 + ch)*16 + w*4)*64 + lane)*8;
#pragma unroll
      for (int mti = 0; mti < 4; ++mti) {
        short8 a = *(const short8*)&ap[(size_t)mti*512];
        acc[mti][0] = __builtin_amdgcn_mfma_f32_16x16x32_bf16(a, b0, acc[mti][0], 0, 0, 0);
        acc[mti][1] = __builtin_amdgcn_mfma_f32_16x16x32_bf16(a, b1, acc[mti][1], 0, 0, 0);
      }
    }
  }
  __syncthreads();

  // ---- frags -> tile[o][33] (C/D layout: row o = quad*4+reg, col x = lane&15) ----
  float* tile = smem;
  float* red = smem + 8448;
#pragma unroll
  for (int mti = 0; mti < 4; ++mti)
#pragma unroll
    for (int nt = 0; nt < 2; ++nt)
#pragma unroll
      for (int r = 0; r < 4; ++r)
        tile[((w*4 + mti)*16 + quad*4 + r)*33 + nt*16 + xb] = acc[mti][nt][r];
  __syncthreads();

  // ---- + static terms, relu (thread = o) ----
  const int o = tid;
  {
    const int ry = (y == 0) ? 0 : ((y == 31) ? 2 : 1);
    const float* hnw = ws + OF_HNW;
    const float bl = hnw[((size_t)(ry*3+0)*NB + n)*CD + o];
    const float bm = hnw[((size_t)(ry*3+1)*NB + n)*CD + o];
    const float br = hnw[((size_t)(ry*3+2)*NB + n)*CD + o];
    const float* sc = ws + OF_SCV + (size_t)(y*32)*CD + o;
#pragma unroll
    for (int x = 0; x < 32; ++x) {
      float v = tile[o*33 + x] + sc[(size_t)x*CD] + (x == 0 ? bl : (x == 31 ? br : bm));
      tile[o*33 + x] = fmaxf(v, 0.f);
    }
  }
  __syncthreads();
  ln_reduce(tile, 33, red, tid);
  const float g = LD(mg, o, bfv), bb = LD(mbv, o, bfv);
  float* tp = ws + OF_T + ((size_t)n*PP + (size_t)y*32)*CD + o;
#pragma unroll
  for (int x = 0; x < 32; ++x)
    tp[(size_t)x*CD] = (tile[o*33 + x] - red[512 + x]) * red[544 + x] * g + bb;
}

// fused K and V projections
__global__ __launch_bounds__(256) void k_kv(const void* __restrict__ ipb, float* __restrict__ ws) {
  __shared__ float smem[9216];
  const int bf = get_bf(ws);
  const int b = blockIdx.x, n = b >> 5, p0 = (b & 31) << 5;
  const int tid = threadIdx.x, o = tid;
  stage36(ws + OF_T + ((size_t)n*PP + p0)*CD, smem, tid);
  __syncthreads();
  float ak[32], av[32];
#pragma unroll
  for (int r = 0; r < 32; ++r) { ak[r] = 0.f; av[r] = 0.f; }
  const float* wk = ws + OF_WKT + o;
  const float* wv = ws + OF_WVT + o;
  for (int c = 0; c < CD; ++c) {
    const float wkc = wk[(size_t)c*CD];
    const float wvc = wv[(size_t)c*CD];
#pragma unroll
    for (int r4 = 0; r4 < 8; ++r4) {
      float4 v = *(const float4*)&smem[c*36 + r4*4];
      ak[r4*4+0] += wkc*v.x; ak[r4*4+1] += wkc*v.y; ak[r4*4+2] += wkc*v.z; ak[r4*4+3] += wkc*v.w;
      av[r4*4+0] += wvc*v.x; av[r4*4+1] += wvc*v.y; av[r4*4+2] += wvc*v.z; av[r4*4+3] += wvc*v.w;
    }
  }
  const float bk = LD(ipb, 256 + o, bf), bv = LD(ipb, 512 + o, bf);
  float* KH = ws + OF_KH + ((size_t)n*PP + p0)*CD + o;
  float* VV = ws + OF_VV + ((size_t)n*PP + p0)*CD + o;
#pragma unroll
  for (int r = 0; r < 32; ++r) { KH[(size_t)r*CD] = ak[r] + bk; VV[(size_t)r*CD] = av[r] + bv; }
}

// cross-batch attention: one wave per (p, h)
__global__ __launch_bounds__(64) void k_attn(int s, float* __restrict__ ws) {
  __shared__ float SQ[16*132], SK[16*132], SV[16*132], SA[16*20];
  const int p = blockIdx.x >> 1, h = blockIdx.x & 1;
  const int lane = threadIdx.x;
  for (int i = lane; i < 16*128; i += 64) {
    const int l = i >> 7, d = i & 127;
    SQ[l*132 + d] = ws[OF_QH + ((size_t)(s*NB + l))*CD + h*128 + d];
    SK[l*132 + d] = ws[OF_KH + ((size_t)l*PP + p)*CD + h*128 + d];
    SV[l*132 + d] = ws[OF_VV + ((size_t)l*PP + p)*CD + h*128 + d];
  }
  __syncthreads();
  const int l = lane >> 2, mg = lane & 3;
  float sc[4];
#pragma unroll
  for (int j = 0; j < 4; ++j) {
    const int m = mg*4 + j;
    float a = 0.f;
    for (int d4 = 0; d4 < 128; d4 += 4) {
      float4 q = *(const float4*)&SQ[l*132 + d4];
      float4 k = *(const float4*)&SK[m*132 + d4];
      a += q.x*k.x + q.y*k.y + q.z*k.z + q.w*k.w;
    }
    sc[j] = a * 0.08838834764831845f;   // 1/sqrt(128)
  }
  float mx = fmaxf(fmaxf(sc[0], sc[1]), fmaxf(sc[2], sc[3]));
  mx = fmaxf(mx, __shfl_xor(mx, 1, 64));
  mx = fmaxf(mx, __shfl_xor(mx, 2, 64));
  float sum = 0.f;
#pragma unroll
  for (int j = 0; j < 4; ++j) { sc[j] = __expf(sc[j] - mx); sum += sc[j]; }
  sum += __shfl_xor(sum, 1, 64);
  sum += __shfl_xor(sum, 2, 64);
  const float inv = 1.f / sum;
#pragma unroll
  for (int j = 0; j < 4; ++j) SA[l*20 + mg*4 + j] = sc[j]*inv;
  __syncthreads();
  float oa[32];
#pragma unroll
  for (int d = 0; d < 32; ++d) oa[d] = 0.f;
  for (int m = 0; m < 16; ++m) {
    const float a = SA[l*20 + m];
#pragma unroll
    for (int d4 = 0; d4 < 8; ++d4) {
      float4 v = *(const float4*)&SV[m*132 + mg*32 + d4*4];
      oa[d4*4+0] += a*v.x; oa[d4*4+1] += a*v.y; oa[d4*4+2] += a*v.z; oa[d4*4+3] += a*v.w;
    }
  }
  float* dst = ws + OF_AO + ((size_t)l*PP + p)*CD + h*128 + mg*32;
#pragma unroll
  for (int d4 = 0; d4 < 8; ++d4)
    *(float4*)&dst[d4*4] = make_float4(oa[d4*4], oa[d4*4+1], oa[d4*4+2], oa[d4*4+3]);
}

// fea = LN(t + attn_o @ out_proj^T + b)   -> OF_KH (aliased)
__global__ __launch_bounds__(256) void k_outproj_ln(const void* __restrict__ opb, const void* __restrict__ ng,
                                                    const void* __restrict__ nbv, float* __restrict__ ws) {
  __shared__ float smem[9216 + 576];
  const int bf = get_bf(ws);
  const int b = blockIdx.x, n = b >> 5, p0 = (b & 31) << 5;
  const int tid = threadIdx.x, o = tid;
  stage36(ws + OF_AO + ((size_t)n*PP + p0)*CD, smem, tid);
  __syncthreads();
  float acc[32];
#pragma unroll
  for (int r = 0; r < 32; ++r) acc[r] = 0.f;
  gemm36(smem, ws + OF_WOT, o, acc);
  const float bo = LD(opb, o, bf);
  const float* tr = ws + OF_T + ((size_t)n*PP + p0)*CD + o;
#pragma unroll
  for (int r = 0; r < 32; ++r) acc[r] += bo + tr[(size_t)r*CD];
  __syncthreads();
#pragma unroll
  for (int r = 0; r < 32; ++r) smem[o*36 + r] = acc[r];
  __syncthreads();
  float* red = smem + 9216;
  ln_reduce(smem, 36, red, tid);
  const float g = LD(ng, o, bf), bb = LD(nbv, o, bf);
  float* fea = ws + OF_KH + ((size_t)n*PP + p0)*CD + o;
#pragma unroll
  for (int r = 0; r < 32; ++r)
    fea[(size_t)r*CD] = (smem[o*36 + r] - red[512 + r]) * red[544 + r] * g + bb;
}

// f2a = relu(fea @ lin1^T + b)  -> OF_VV (aliased)
__global__ __launch_bounds__(256) void k_lin1(const void* __restrict__ l1b, float* __restrict__ ws) {
  __shared__ float smem[9216];
  const int bf = get_bf(ws);
  const int b = blockIdx.x, n = b >> 5, p0 = (b & 31) << 5;
  const int tid = threadIdx.x, o = tid;
  stage36(ws + OF_KH + ((size_t)n*PP + p0)*CD, smem, tid);
  __syncthreads();
  float acc[32];
#pragma unroll
  for (int r = 0; r < 32; ++r) acc[r] = 0.f;
  gemm36(smem, ws + OF_W1T, o, acc);
  const float bb = LD(l1b, o, bf);
  float* dst = ws + OF_VV + ((size_t)n*PP + p0)*CD + o;
#pragma unroll
  for (int r = 0; r < 32; ++r) dst[(size_t)r*CD] = fmaxf(acc[r] + bb, 0.f);
}

// fea2 = LN(fea + f2a @ lin2^T + b); if active: feat_bf16[n][p][c] = fea2
__global__ __launch_bounds__(256) void k_lin2(const void* __restrict__ l2b, const void* __restrict__ nfg,
                                              const void* __restrict__ nfb, const int* __restrict__ words,
                                              int s, float* __restrict__ ws) {
  __shared__ float smem[9216 + 576];
  const int bf = get_bf(ws);
  const int b = blockIdx.x, n = b >> 5, p0 = (b & 31) << 5;
  const int tid = threadIdx.x, o = tid;
  stage36(ws + OF_VV + ((size_t)n*PP + p0)*CD, smem, tid);
  __syncthreads();
  float acc[32];
#pragma unroll
  for (int r = 0; r < 32; ++r) acc[r] = 0.f;
  gemm36(smem, ws + OF_W2T, o, acc);
  const float bb = LD(l2b, o, bf);
  const float* fer = ws + OF_KH + ((size_t)n*PP + p0)*CD + o;
#pragma unroll
  for (int r = 0; r < 32; ++r) acc[r] += bb + fer[(size_t)r*CD];
  __syncthreads();
#pragma unroll
  for (int r = 0; r < 32; ++r) smem[o*36 + r] = acc[r];
  __syncthreads();
  float* red = smem + 9216;
  ln_reduce(smem, 36, red, tid);
  const float g = LD(nfg, o, bf), b2 = LD(nfb, o, bf);
#pragma unroll
  for (int r = 0; r < 32; ++r)
    smem[o*36 + r] = (smem[o*36 + r] - red[512 + r]) * red[544 + r] * g + b2;
  __syncthreads();
  if (words[s] != 0) {
    bf16* fbd = (bf16*)(ws + OF_FEATB);
#pragma unroll 1
    for (int r = 0; r < 32; ++r)
      fbd[((size_t)(n*PP + p0 + r))*CD + o] = f2bf(smem[o*36 + r]);
  }
}

// output [n][c][p] from bf16 feat [n][p][c]
__global__ __launch_bounds__(256) void k_final(const float* __restrict__ ws, void* __restrict__ out) {
  const int bf = get_bf(ws);
  const size_t i = (size_t)blockIdx.x*256 + threadIdx.x;
  const int n = (int)(i >> 18), c = (int)((i >> 10) & 255), p = (int)(i & 1023);
  const bf16* fb = (const bf16*)(ws + OF_FEATB);
  float v = bf2f(fb[((size_t)(n*PP + p))*CD + c]);
  if (bf) ((bf16*)out)[i] = f2bf(v);
  else    ((float*)out)[i] = v;
}

extern "C" void kernel_launch(void* const* d_in, const int* in_sizes, int n_in,
                              void* d_out, int out_size, void* d_ws, size_t ws_size,
                              hipStream_t stream) {
  (void)in_sizes; (void)n_in; (void)out_size; (void)ws_size;
  const void* hn      = d_in[1];
  const void* feature = d_in[2];
  const void* emb     = d_in[3];
  const int*  words   = (const int*)d_in[4];
  const void* qw  = d_in[5];
  const void* qb  = d_in[6];
  const void* mw  = d_in[7];
  const void* mg  = d_in[8];
  const void* mb  = d_in[9];
  const void* ipw = d_in[10];
  const void* ipb = d_in[11];
  const void* opw = d_in[12];
  const void* opb = d_in[13];
  const void* ng  = d_in[14];
  const void* nb  = d_in[15];
  const void* l1w = d_in[16];
  const void* l1b = d_in[17];
  const void* l2w = d_in[18];
  const void* l2b = d_in[19];
  const void* nfg = d_in[20];
  const void* nfb = d_in[21];
  float* ws = (float*)d_ws;

  k_detect<<<1, 64, 0, stream>>>(mg, ws);
  k_init<<<NB*PP, 256, 0, stream>>>(feature, ws);
  k_qh<<<SEQL*NB, 256, 0, stream>>>(emb, qw, qb, ipw, ipb, ws);
  k_wregion<<<(9*CD*HND)/256, 256, 0, stream>>>(mw, ws);
  k_hnw<<<9*NB, 256, 0, stream>>>(hn, ws);
  k_sconv<<<PP, 256, 0, stream>>>(mw, ws);
  k_wpack<<<(9*8*16*64*8)/256, 256, 0, stream>>>(mw, ws);
  k_wT<<<5*CD, 256, 0, stream>>>(ipw, opw, l1w, l2w, ws);

  for (int s = 0; s < SEQL; ++s) {
    k_conv_mfma<<<NB*32, 256, 0, stream>>>(mg, mb, ws);
    k_kv<<<NB*32, 256, 0, stream>>>(ipb, ws);
    k_attn<<<PP*2, 64, 0, stream>>>(s, ws);
    k_outproj_ln<<<NB*32, 256, 0, stream>>>(opb, ng, nb, ws);
    k_lin1<<<NB*32, 256, 0, stream>>>(l1b, ws);
    k_lin2<<<NB*32, 256, 0, stream>>>(l2b, nfg, nfb, words, s, ws);
  }
  k_final<<<NB*CD*PP/256, 256, 0, stream>>>(ws, (void*)d_out);
}

// Round 4
// 2616.596 us; speedup vs baseline: 4.6292x; 2.3491x over previous
//
#include <hip/hip_runtime.h>
#include <hip/hip_bf16.h>
#include <cstddef>

typedef __hip_bfloat16 bf16;
typedef short short8 __attribute__((ext_vector_type(8)));
typedef float float4v __attribute__((ext_vector_type(4)));
#define DEV static __device__ __forceinline__

constexpr int NB = 16;     // batch
constexpr int SEQL = 20;
constexpr int CD = 256;    // VD
constexpr int PP = 1024;   // 32*32
constexpr int HND = 512;
constexpr int EMBD = 300;
constexpr int CIN = 776;   // 256 + 8 + 512

// ---- workspace layout (float element offsets); bf16 buffers are [n][p][c] ----
constexpr size_t SZB = (size_t)NB * PP * CD / 2;             // floats per bf16 NPC buffer
constexpr size_t OF_FEATB = 0;                               // running feature (bf16)
constexpr size_t OF_TB   = 1*SZB;                            // t (bf16)
constexpr size_t OF_KHB  = 2*SZB;                            // kh (bf16)
constexpr size_t OF_VVB  = 3*SZB;                            // vv (bf16)
constexpr size_t OF_AOB  = 4*SZB;                            // attn out (bf16)
constexpr size_t OF_FEA  = 5*SZB;                            // fea (bf16)
constexpr size_t OF_F2A  = 6*SZB;                            // f2a (bf16)
constexpr size_t OF_QH   = 7*SZB;                            // qh [s][n][c] fp32
constexpr size_t OF_HNW  = OF_QH  + (size_t)SEQL*NB*CD;      // hnW [r][n][o] fp32
constexpr size_t OF_SCV  = OF_HNW + (size_t)9*NB*CD;         // sconv [p][o] fp32
constexpr size_t OF_WRG  = OF_SCV + (size_t)PP*CD;           // W_region [r][o][c] fp32
constexpr size_t OF_AW   = OF_WRG + (size_t)9*CD*HND;        // conv W A-frags (589,824 bf16)
constexpr size_t OF_PK   = OF_AW  + (size_t)294912;          // linear W B-frags: 5 x 65,536 bf16
constexpr size_t OF_FLAG = OF_PK  + (size_t)163840;          // dtype flag
// end ~= 67.5 MB

DEV float bf2f(bf16 v) { return __bfloat162float(v); }
DEV bf16 f2bf(float v) { return __float2bfloat16(v); }

DEV float LD(const void* p, size_t i, int bf) {
  return bf ? __bfloat162float(((const bf16*)p)[i]) : ((const float*)p)[i];
}
DEV int get_bf(const float* ws) { return ((const int*)ws)[OF_FLAG]; }

__global__ void k_detect(const void* g, float* ws) {
  if (threadIdx.x == 0 && blockIdx.x == 0) {
    unsigned w = *(const unsigned*)g;
    ((int*)ws)[OF_FLAG] = ((w & 0xFFFFu) != 0u) ? 1 : 0;
  }
}

// LN reduction: tile[o][x], stride; red[512+x]=mean, red[544+x]=rstd, x in [0,32)
DEV void ln_reduce(const float* tile, int stride, float* red, int tid) {
  const int x = tid & 31, seg = tid >> 5;
  float s = 0.f, sq = 0.f;
  for (int i = 0; i < 32; ++i) {
    float v = tile[(seg*32 + i)*stride + x];
    s += v; sq += v*v;
  }
  red[seg*32 + x] = s;
  red[256 + seg*32 + x] = sq;
  __syncthreads();
  if (tid < 32) {
    float ts = 0.f, tq = 0.f;
    for (int g = 0; g < 8; ++g) { ts += red[g*32 + tid]; tq += red[256 + g*32 + tid]; }
    float m = ts * (1.f/CD);
    float var = tq * (1.f/CD) - m*m;
    red[512 + tid] = m;
    red[544 + tid] = 1.f / sqrtf(var + 1e-5f);
  }
  __syncthreads();
}

// stage 32 rows x 256 cols bf16 -> LDS As[32][264]
DEV void stageA(const bf16* __restrict__ src, short* __restrict__ As, int tid) {
  const int r = tid >> 3, c0 = (tid & 7)*32;
#pragma unroll
  for (int i = 0; i < 4; ++i) {
    short8 v = *(const short8*)&src[(size_t)r*CD + c0 + i*8];
    *(short8*)&As[r*264 + c0 + i*8] = v;
  }
}

// C[p=32][c=256] = A[32][256] x W^T via MFMA; wave w owns n-tiles w*4..w*4+3, m-tiles 0..1
DEV void mfma_core(const short* __restrict__ As, const short* __restrict__ PKg,
                   int w, int lane, float4v acc[2][4]) {
  const int xb = lane & 15, quad = lane >> 4;
#pragma unroll 1
  for (int ch = 0; ch < 8; ++ch) {
    short8 a0 = *(const short8*)&As[xb*264 + ch*32 + quad*8];
    short8 a1 = *(const short8*)&As[(16+xb)*264 + ch*32 + quad*8];
#pragma unroll
    for (int nti = 0; nti < 4; ++nti) {
      short8 bfr = *(const short8*)&PKg[(size_t)(((w*4 + nti)*8 + ch)*512) + lane*8];
      acc[0][nti] = __builtin_amdgcn_mfma_f32_16x16x32_bf16(a0, bfr, acc[0][nti], 0, 0, 0);
      acc[1][nti] = __builtin_amdgcn_mfma_f32_16x16x32_bf16(a1, bfr, acc[1][nti], 0, 0, 0);
    }
  }
}

// ---------------- prep kernels ----------------

// transpose input feature [n][c][p] -> bf16 [n][p][c]
__global__ __launch_bounds__(256) void k_init(const void* __restrict__ f, float* __restrict__ ws) {
  const int bf = get_bf(ws);
  const int b = blockIdx.x;            // (n,p)
  const int n = b >> 10, p = b & 1023;
  const int c = threadIdx.x;
  bf16* fb = (bf16*)(ws + OF_FEATB);
  fb[(size_t)b*CD + c] = f2bf(LD(f, ((size_t)n*CD + c)*PP + p, bf));
}

// q = relu(emb @ qconv_w^T + qb); qh = q @ Wq^T + bq
__global__ __launch_bounds__(256) void k_qh(const void* __restrict__ emb, const void* __restrict__ qw,
                                            const void* __restrict__ qb, const void* __restrict__ ipw,
                                            const void* __restrict__ ipb, float* __restrict__ ws) {
  const int bf = get_bf(ws);
  const int b = blockIdx.x, s = b / NB, n = b % NB;
  const int o = threadIdx.x;
  __shared__ float se[EMBD];
  __shared__ float sq[CD];
  for (int i = o; i < EMBD; i += CD) se[i] = LD(emb, ((size_t)n*SEQL + s)*EMBD + i, bf);
  __syncthreads();
  float a = LD(qb, o, bf);
  if (bf) {
    const bf16* wr = (const bf16*)qw + (size_t)o*EMBD;
    for (int c = 0; c < EMBD; ++c) a += se[c]*bf2f(wr[c]);
  } else {
    const float* wr = (const float*)qw + (size_t)o*EMBD;
    for (int c = 0; c < EMBD; ++c) a += se[c]*wr[c];
  }
  sq[o] = fmaxf(a, 0.f);
  __syncthreads();
  float a2 = LD(ipb, o, bf);
  if (bf) {
    const bf16* wq = (const bf16*)ipw + (size_t)o*CD;
    for (int c = 0; c < CD; ++c) a2 += sq[c]*bf2f(wq[c]);
  } else {
    const float* wq = (const float*)ipw + (size_t)o*CD;
    for (int c = 0; c < CD; ++c) a2 += sq[c]*wq[c];
  }
  ws[OF_QH + ((size_t)s*NB + n)*CD + o] = a2;
}

// Tap-sums of hn-channel conv weights per border pattern
__global__ __launch_bounds__(256) void k_wregion(const void* __restrict__ mw, float* __restrict__ ws) {
  const int bf = get_bf(ws);
  const int gid = blockIdx.x*256 + threadIdx.x;
  const int c = gid & (HND-1);
  const int o = (gid >> 9) & (CD-1);
  const int r = gid >> 17;
  const int ry = r/3, rx = r%3;
  float s = 0.f;
  for (int dy = 0; dy < 3; ++dy) {
    if (ry == 0 && dy == 0) continue;
    if (ry == 2 && dy == 2) continue;
    for (int dx = 0; dx < 3; ++dx) {
      if (rx == 0 && dx == 0) continue;
      if (rx == 2 && dx == 2) continue;
      s += LD(mw, ((size_t)o*CIN + 264 + c)*9 + dy*3 + dx, bf);
    }
  }
  ws[OF_WRG + gid] = s;
}

// hnW[r][n][o] = hn[n] . W_region[r][o][:]
__global__ __launch_bounds__(256) void k_hnw(const void* __restrict__ hn, float* __restrict__ ws) {
  const int bf = get_bf(ws);
  const int b = blockIdx.x, r = b / NB, n = b % NB;
  const int o = threadIdx.x;
  __shared__ float sh[HND];
  for (int i = o; i < HND; i += CD) sh[i] = LD(hn, (size_t)n*HND + i, bf);
  __syncthreads();
  const float* wr = ws + OF_WRG + ((size_t)r*CD + o)*HND;
  float a = 0.f;
  for (int c = 0; c < HND; ++c) a += sh[c]*wr[c];
  ws[OF_HNW + ((size_t)r*NB + n)*CD + o] = a;
}

DEV float spat(int c, int yy, int xx) {
  switch (c) {
    case 0: return xx*(1.f/16) - 1.f;
    case 1: return yy*(1.f/16) - 1.f;
    case 2: return (xx+1)*(1.f/16) - 1.f;
    case 3: return (yy+1)*(1.f/16) - 1.f;
    case 4: return (xx+0.5f)*(1.f/16) - 1.f;
    case 5: return (yy+0.5f)*(1.f/16) - 1.f;
    default: return 1.f/32;
  }
}

// sconv[p][o] = conv contribution of the 8 spatial channels
__global__ __launch_bounds__(256) void k_sconv(const void* __restrict__ mw, float* __restrict__ ws) {
  const int bf = get_bf(ws);
  const int p = blockIdx.x, o = threadIdx.x;
  const int y = p >> 5, x = p & 31;
  float a = 0.f;
  for (int c = 0; c < 8; ++c)
    for (int dy = 0; dy < 3; ++dy) {
      int yy = y + dy - 1; if ((unsigned)yy >= 32u) continue;
      for (int dx = 0; dx < 3; ++dx) {
        int xx = x + dx - 1; if ((unsigned)xx >= 32u) continue;
        a += LD(mw, ((size_t)o*CIN + 256 + c)*9 + dy*3 + dx, bf) * spat(c, yy, xx);
      }
    }
  ws[OF_SCV + (size_t)p*CD + o] = a;
}

// conv feat weights -> MFMA A-frag order: AW[tap][ch][mt][lane][j]
__global__ __launch_bounds__(256) void k_wpack(const void* __restrict__ mw, float* __restrict__ ws) {
  const int bf = get_bf(ws);
  const int idx = blockIdx.x*256 + threadIdx.x;
  const int j = idx & 7;
  const int lane = (idx >> 3) & 63;
  const int mt = (idx >> 9) & 15;
  const int ch = (idx >> 13) & 7;
  const int tap = idx >> 16;
  const int o = mt*16 + (lane & 15);
  const int c = ch*32 + (lane >> 4)*8 + j;
  bf16* aw = (bf16*)(ws + OF_AW);
  aw[idx] = f2bf(LD(mw, ((size_t)o*CIN + c)*9 + tap, bf));
}

// linear weights -> MFMA B-frag order: PK[g][nt][ch][lane][j]; g: 0=Wk 1=Wv 2=Wo 3=W1 4=W2
__global__ __launch_bounds__(256) void k_wpackB(const void* __restrict__ ipw, const void* __restrict__ opw,
                                                const void* __restrict__ l1w, const void* __restrict__ l2w,
                                                float* __restrict__ ws) {
  const int bf = get_bf(ws);
  const int idx = blockIdx.x*256 + threadIdx.x;       // 5*65536
  const int j = idx & 7;
  const int lane = (idx >> 3) & 63;
  const int ch = (idx >> 9) & 7;
  const int nt = (idx >> 12) & 15;
  const int g = idx >> 16;
  const int o = nt*16 + (lane & 15);
  const int k = ch*32 + (lane >> 4)*8 + j;
  float v;
  switch (g) {
    case 0: v = LD(ipw, ((size_t)(256 + o))*CD + k, bf); break;
    case 1: v = LD(ipw, ((size_t)(512 + o))*CD + k, bf); break;
    case 2: v = LD(opw, (size_t)o*CD + k, bf);           break;
    case 3: v = LD(l1w, (size_t)o*CD + k, bf);           break;
    default: v = LD(l2w, (size_t)o*CD + k, bf);          break;
  }
  ((bf16*)(ws + OF_PK))[idx] = f2bf(v);
}

// ---------------- per-step kernels ----------------

// 3x3 conv via MFMA + static terms + relu + LN -> t bf16 [n][p][c]
__global__ __launch_bounds__(256) void k_conv_mfma(const void* __restrict__ mg, const void* __restrict__ mbv,
                                                   float* __restrict__ ws) {
  __shared__ float smem[13464];            // X3T[3][34][264] bf16; reused as tile[256][33]+red
  bf16* Xs = (bf16*)smem;
  const int bfv = get_bf(ws);
  const int b = blockIdx.x, n = b >> 5, y = b & 31;
  const int tid = threadIdx.x;
  const int w = tid >> 6, lane = tid & 63;
  const bf16* fb = (const bf16*)(ws + OF_FEATB);

  const short8 zero8 = {0,0,0,0,0,0,0,0};
  if (tid < 192) {
    const int r = tid >> 6, xp = ((tid >> 5) & 1) * 33, c0 = (tid & 31)*8;
    *(short8*)&Xs[(r*34 + xp)*264 + c0] = zero8;
  }
#pragma unroll
  for (int u = 0; u < 12; ++u) {
    const int lin = u*256 + tid;
    const int cgrp = lin & 31, xl = (lin >> 5) & 31, r = lin >> 10;
    const int row = y + r - 1;
    short8 v = zero8;
    if ((unsigned)row < 32u)
      v = *(const short8*)&fb[((size_t)(n*PP + row*32 + xl))*CD + cgrp*8];
    *(short8*)&Xs[(r*34 + 1 + xl)*264 + cgrp*8] = v;
  }
  __syncthreads();

  float4v acc[4][2];
#pragma unroll
  for (int mti = 0; mti < 4; ++mti) { acc[mti][0] = (float4v)0.f; acc[mti][1] = (float4v)0.f; }
  const bf16* AW = (const bf16*)(ws + OF_AW);
  const int xb = lane & 15, quad = lane >> 4;
#pragma unroll 1
  for (int tap = 0; tap < 9; ++tap) {
    const int dy = tap/3, dx = tap - dy*3;
#pragma unroll 1
    for (int ch = 0; ch < 8; ++ch) {
      short8 b0 = *(const short8*)&Xs[(dy*34 + xb + dx)*264 + ch*32 + quad*8];
      short8 b1 = *(const short8*)&Xs[(dy*34 + xb + 16 + dx)*264 + ch*32 + quad*8];
      const bf16* ap = AW + (((size_t)(tap*8 + ch)*16 + w*4)*64 + lane)*8;
#pragma unroll
      for (int mti = 0; mti < 4; ++mti) {
        short8 a = *(const short8*)&ap[(size_t)mti*512];
        acc[mti][0] = __builtin_amdgcn_mfma_f32_16x16x32_bf16(a, b0, acc[mti][0], 0, 0, 0);
        acc[mti][1] = __builtin_amdgcn_mfma_f32_16x16x32_bf16(a, b1, acc[mti][1], 0, 0, 0);
      }
    }
  }
  __syncthreads();

  float* tile = smem;
  float* red = smem + 8448;
#pragma unroll
  for (int mti = 0; mti < 4; ++mti)
#pragma unroll
    for (int nt = 0; nt < 2; ++nt)
#pragma unroll
      for (int r = 0; r < 4; ++r)
        tile[((w*4 + mti)*16 + quad*4 + r)*33 + nt*16 + xb] = acc[mti][nt][r];
  __syncthreads();

  const int o = tid;
  {
    const int ry = (y == 0) ? 0 : ((y == 31) ? 2 : 1);
    const float* hnw = ws + OF_HNW;
    const float bl = hnw[((size_t)(ry*3+0)*NB + n)*CD + o];
    const float bm = hnw[((size_t)(ry*3+1)*NB + n)*CD + o];
    const float br = hnw[((size_t)(ry*3+2)*NB + n)*CD + o];
    const float* sc = ws + OF_SCV + (size_t)(y*32)*CD + o;
#pragma unroll
    for (int x = 0; x < 32; ++x) {
      float v = tile[o*33 + x] + sc[(size_t)x*CD] + (x == 0 ? bl : (x == 31 ? br : bm));
      tile[o*33 + x] = fmaxf(v, 0.f);
    }
  }
  __syncthreads();
  ln_reduce(tile, 33, red, tid);
  const float g = LD(mg, o, bfv), bb = LD(mbv, o, bfv);
  bf16* tp = (bf16*)(ws + OF_TB) + ((size_t)n*PP + (size_t)y*32)*CD + o;
#pragma unroll
  for (int x = 0; x < 32; ++x)
    tp[(size_t)x*CD] = f2bf((tile[o*33 + x] - red[512 + x]) * red[544 + x] * g + bb);
}

// K and V projections via MFMA, direct frag store
__global__ __launch_bounds__(256) void k_kv_mfma(const void* __restrict__ ipb, float* __restrict__ ws) {
  __shared__ short As[32*264];
  const int bf = get_bf(ws);
  const int b = blockIdx.x, n = b >> 5, p0 = (b & 31) << 5;
  const int tid = threadIdx.x, w = tid >> 6, lane = tid & 63;
  stageA((const bf16*)(ws + OF_TB) + ((size_t)n*PP + p0)*CD, As, tid);
  __syncthreads();
  const short* PK = (const short*)(ws + OF_PK);
  const int xb = lane & 15, quad = lane >> 4;
#pragma unroll 1
  for (int G = 0; G < 2; ++G) {
    float4v acc[2][4];
#pragma unroll
    for (int mt = 0; mt < 2; ++mt)
#pragma unroll
      for (int nti = 0; nti < 4; ++nti) acc[mt][nti] = (float4v)0.f;
    mfma_core(As, PK + (size_t)G*65536, w, lane, acc);
    bf16* dst = (bf16*)(ws + (G ? OF_VVB : OF_KHB)) + ((size_t)n*PP + p0)*CD;
#pragma unroll
    for (int nti = 0; nti < 4; ++nti) {
      const int c = (w*4 + nti)*16 + xb;
      const float bias = LD(ipb, (size_t)(G+1)*256 + c, bf);
#pragma unroll
      for (int mt = 0; mt < 2; ++mt)
#pragma unroll
        for (int r = 0; r < 4; ++r)
          dst[(size_t)(mt*16 + quad*4 + r)*CD + c] = f2bf(acc[mt][nti][r] + bias);
    }
  }
}

// cross-batch attention: one wave per (p, h); bf16 K/V, fp32 math
__global__ __launch_bounds__(64) void k_attn(int s, float* __restrict__ ws) {
  __shared__ float SQ[16*132], SK[16*132], SV[16*132], SA[16*20];
  const int p = blockIdx.x >> 1, h = blockIdx.x & 1;
  const int lane = threadIdx.x;
  const bf16* khb = (const bf16*)(ws + OF_KHB);
  const bf16* vvb = (const bf16*)(ws + OF_VVB);
  for (int i = lane; i < 16*128; i += 64) {
    const int l = i >> 7, d = i & 127;
    SQ[l*132 + d] = ws[OF_QH + ((size_t)(s*NB + l))*CD + h*128 + d];
    SK[l*132 + d] = bf2f(khb[((size_t)l*PP + p)*CD + h*128 + d]);
    SV[l*132 + d] = bf2f(vvb[((size_t)l*PP + p)*CD + h*128 + d]);
  }
  __syncthreads();
  const int l = lane >> 2, mg = lane & 3;
  float sc[4];
#pragma unroll
  for (int j = 0; j < 4; ++j) {
    const int m = mg*4 + j;
    float a = 0.f;
    for (int d4 = 0; d4 < 128; d4 += 4) {
      float4 q = *(const float4*)&SQ[l*132 + d4];
      float4 k = *(const float4*)&SK[m*132 + d4];
      a += q.x*k.x + q.y*k.y + q.z*k.z + q.w*k.w;
    }
    sc[j] = a * 0.08838834764831845f;   // 1/sqrt(128)
  }
  float mx = fmaxf(fmaxf(sc[0], sc[1]), fmaxf(sc[2], sc[3]));
  mx = fmaxf(mx, __shfl_xor(mx, 1, 64));
  mx = fmaxf(mx, __shfl_xor(mx, 2, 64));
  float sum = 0.f;
#pragma unroll
  for (int j = 0; j < 4; ++j) { sc[j] = __expf(sc[j] - mx); sum += sc[j]; }
  sum += __shfl_xor(sum, 1, 64);
  sum += __shfl_xor(sum, 2, 64);
  const float inv = 1.f / sum;
#pragma unroll
  for (int j = 0; j < 4; ++j) SA[l*20 + mg*4 + j] = sc[j]*inv;
  __syncthreads();
  float oa[32];
#pragma unroll
  for (int d = 0; d < 32; ++d) oa[d] = 0.f;
  for (int m = 0; m < 16; ++m) {
    const float a = SA[l*20 + m];
#pragma unroll
    for (int d4 = 0; d4 < 8; ++d4) {
      float4 v = *(const float4*)&SV[m*132 + mg*32 + d4*4];
      oa[d4*4+0] += a*v.x; oa[d4*4+1] += a*v.y; oa[d4*4+2] += a*v.z; oa[d4*4+3] += a*v.w;
    }
  }
  bf16* dst = (bf16*)(ws + OF_AOB) + ((size_t)l*PP + p)*CD + h*128 + mg*32;
#pragma unroll
  for (int d = 0; d < 32; ++d) dst[d] = f2bf(oa[d]);
}

// fea = LN(t + ao @ Wo^T + b) -> bf16
__global__ __launch_bounds__(256) void k_outproj_mfma(const void* __restrict__ opb, const void* __restrict__ ng,
                                                      const void* __restrict__ nbv, float* __restrict__ ws) {
  __shared__ float smem[9024];             // As(16.9KB) then tile[256][33]+red
  short* As = (short*)smem;
  const int bf = get_bf(ws);
  const int b = blockIdx.x, n = b >> 5, p0 = (b & 31) << 5;
  const int tid = threadIdx.x, w = tid >> 6, lane = tid & 63;
  stageA((const bf16*)(ws + OF_AOB) + ((size_t)n*PP + p0)*CD, As, tid);
  __syncthreads();
  float4v acc[2][4];
#pragma unroll
  for (int mt = 0; mt < 2; ++mt)
#pragma unroll
    for (int nti = 0; nti < 4; ++nti) acc[mt][nti] = (float4v)0.f;
  mfma_core(As, (const short*)(ws + OF_PK) + (size_t)2*65536, w, lane, acc);
  __syncthreads();    // done with As before tile overwrite
  float* tile = smem;
  float* red = smem + 8448;
  const int xb = lane & 15, quad = lane >> 4;
#pragma unroll
  for (int nti = 0; nti < 4; ++nti)
#pragma unroll
    for (int mt = 0; mt < 2; ++mt)
#pragma unroll
      for (int r = 0; r < 4; ++r)
        tile[((w*4 + nti)*16 + xb)*33 + mt*16 + quad*4 + r] = acc[mt][nti][r];
  __syncthreads();
  const int o = tid;
  const float bo = LD(opb, o, bf);
  const bf16* tb = (const bf16*)(ws + OF_TB) + ((size_t)n*PP + p0)*CD + o;
#pragma unroll
  for (int x = 0; x < 32; ++x)
    tile[o*33 + x] += bo + bf2f(tb[(size_t)x*CD]);
  __syncthreads();
  ln_reduce(tile, 33, red, tid);
  const float g = LD(ng, o, bf), bb = LD(nbv, o, bf);
  bf16* fea = (bf16*)(ws + OF_FEA) + ((size_t)n*PP + p0)*CD + o;
#pragma unroll
  for (int x = 0; x < 32; ++x)
    fea[(size_t)x*CD] = f2bf((tile[o*33 + x] - red[512 + x]) * red[544 + x] * g + bb);
}

// f2a = relu(fea @ W1^T + b) -> bf16, direct frag store
__global__ __launch_bounds__(256) void k_lin1_mfma(const void* __restrict__ l1b, float* __restrict__ ws) {
  __shared__ short As[32*264];
  const int bf = get_bf(ws);
  const int b = blockIdx.x, n = b >> 5, p0 = (b & 31) << 5;
  const int tid = threadIdx.x, w = tid >> 6, lane = tid & 63;
  stageA((const bf16*)(ws + OF_FEA) + ((size_t)n*PP + p0)*CD, As, tid);
  __syncthreads();
  float4v acc[2][4];
#pragma unroll
  for (int mt = 0; mt < 2; ++mt)
#pragma unroll
    for (int nti = 0; nti < 4; ++nti) acc[mt][nti] = (float4v)0.f;
  mfma_core(As, (const short*)(ws + OF_PK) + (size_t)3*65536, w, lane, acc);
  const int xb = lane & 15, quad = lane >> 4;
  bf16* dst = (bf16*)(ws + OF_F2A) + ((size_t)n*PP + p0)*CD;
#pragma unroll
  for (int nti = 0; nti < 4; ++nti) {
    const int c = (w*4 + nti)*16 + xb;
    const float bias = LD(l1b, c, bf);
#pragma unroll
    for (int mt = 0; mt < 2; ++mt)
#pragma unroll
      for (int r = 0; r < 4; ++r)
        dst[(size_t)(mt*16 + quad*4 + r)*CD + c] = f2bf(fmaxf(acc[mt][nti][r] + bias, 0.f));
  }
}

// fea2 = LN(fea + f2a @ W2^T + b); if active commit to featb
__global__ __launch_bounds__(256) void k_lin2_mfma(const void* __restrict__ l2b, const void* __restrict__ nfg,
                                                   const void* __restrict__ nfb, const int* __restrict__ words,
                                                   int s, float* __restrict__ ws) {
  __shared__ float smem[9024];
  short* As = (short*)smem;
  const int bf = get_bf(ws);
  const int b = blockIdx.x, n = b >> 5, p0 = (b & 31) << 5;
  const int tid = threadIdx.x, w = tid >> 6, lane = tid & 63;
  stageA((const bf16*)(ws + OF_F2A) + ((size_t)n*PP + p0)*CD, As, tid);
  __syncthreads();
  float4v acc[2][4];
#pragma unroll
  for (int mt = 0; mt < 2; ++mt)
#pragma unroll
    for (int nti = 0; nti < 4; ++nti) acc[mt][nti] = (float4v)0.f;
  mfma_core(As, (const short*)(ws + OF_PK) + (size_t)4*65536, w, lane, acc);
  __syncthreads();
  float* tile = smem;
  float* red = smem + 8448;
  const int xb = lane & 15, quad = lane >> 4;
#pragma unroll
  for (int nti = 0; nti < 4; ++nti)
#pragma unroll
    for (int mt = 0; mt < 2; ++mt)
#pragma unroll
      for (int r = 0; r < 4; ++r)
        tile[((w*4 + nti)*16 + xb)*33 + mt*16 + quad*4 + r] = acc[mt][nti][r];
  __syncthreads();
  const int o = tid;
  const float bb = LD(l2b, o, bf);
  const bf16* fea = (const bf16*)(ws + OF_FEA) + ((size_t)n*PP + p0)*CD + o;
#pragma unroll
  for (int x = 0; x < 32; ++x)
    tile[o*33 + x] += bb + bf2f(fea[(size_t)x*CD]);
  __syncthreads();
  ln_reduce(tile, 33, red, tid);
  if (words[s] != 0) {
    const float g = LD(nfg, o, bf), b2 = LD(nfb, o, bf);
    bf16* fbd = (bf16*)(ws + OF_FEATB) + ((size_t)n*PP + p0)*CD + o;
#pragma unroll
    for (int x = 0; x < 32; ++x)
      fbd[(size_t)x*CD] = f2bf((tile[o*33 + x] - red[512 + x]) * red[544 + x] * g + b2);
  }
}

// output [n][c][p] from bf16 feat [n][p][c]
__global__ __launch_bounds__(256) void k_final(const float* __restrict__ ws, void* __restrict__ out) {
  const int bf = get_bf(ws);
  const size_t i = (size_t)blockIdx.x*256 + threadIdx.x;
  const int n = (int)(i >> 18), c = (int)((i >> 10) & 255), p = (int)(i & 1023);
  const bf16* fb = (const bf16*)(ws + OF_FEATB);
  float v = bf2f(fb[((size_t)(n*PP + p))*CD + c]);
  if (bf) ((bf16*)out)[i] = f2bf(v);
  else    ((float*)out)[i] = v;
}

extern "C" void kernel_launch(void* const* d_in, const int* in_sizes, int n_in,
                              void* d_out, int out_size, void* d_ws, size_t ws_size,
                              hipStream_t stream) {
  (void)in_sizes; (void)n_in; (void)out_size; (void)ws_size;
  const void* hn      = d_in[1];
  const void* feature = d_in[2];
  const void* emb     = d_in[3];
  const int*  words   = (const int*)d_in[4];
  const void* qw  = d_in[5];
  const void* qb  = d_in[6];
  const void* mw  = d_in[7];
  const void* mg  = d_in[8];
  const void* mb  = d_in[9];
  const void* ipw = d_in[10];
  const void* ipb = d_in[11];
  const void* opw = d_in[12];
  const void* opb = d_in[13];
  const void* ng  = d_in[14];
  const void* nb  = d_in[15];
  const void* l1w = d_in[16];
  const void* l1b = d_in[17];
  const void* l2w = d_in[18];
  const void* l2b = d_in[19];
  const void* nfg = d_in[20];
  const void* nfb = d_in[21];
  float* ws = (float*)d_ws;

  k_detect<<<1, 64, 0, stream>>>(mg, ws);
  k_init<<<NB*PP, 256, 0, stream>>>(feature, ws);
  k_qh<<<SEQL*NB, 256, 0, stream>>>(emb, qw, qb, ipw, ipb, ws);
  k_wregion<<<(9*CD*HND)/256, 256, 0, stream>>>(mw, ws);
  k_hnw<<<9*NB, 256, 0, stream>>>(hn, ws);
  k_sconv<<<PP, 256, 0, stream>>>(mw, ws);
  k_wpack<<<(9*8*16*64*8)/256, 256, 0, stream>>>(mw, ws);
  k_wpackB<<<(5*65536)/256, 256, 0, stream>>>(ipw, opw, l1w, l2w, ws);

  for (int s = 0; s < SEQL; ++s) {
    k_conv_mfma<<<NB*32, 256, 0, stream>>>(mg, mb, ws);
    k_kv_mfma<<<NB*32, 256, 0, stream>>>(ipb, ws);
    k_attn<<<PP*2, 64, 0, stream>>>(s, ws);
    k_outproj_mfma<<<NB*32, 256, 0, stream>>>(opb, ng, nb, ws);
    k_lin1_mfma<<<NB*32, 256, 0, stream>>>(l1b, ws);
    k_lin2_mfma<<<NB*32, 256, 0, stream>>>(l2b, nfg, nfb, words, s, ws);
  }
  k_final<<<NB*CD*PP/256, 256, 0, stream>>>(ws, (void*)d_out);
}

// Round 5
// 1896.632 us; speedup vs baseline: 6.3864x; 1.3796x over previous
//
#include <hip/hip_runtime.h>
#include <hip/hip_bf16.h>
#include <cstddef>

typedef __hip_bfloat16 bf16;
typedef short short8 __attribute__((ext_vector_type(8)));
typedef float float4v __attribute__((ext_vector_type(4)));
#define DEV static __device__ __forceinline__

constexpr int NB = 16;     // batch
constexpr int SEQL = 20;
constexpr int CD = 256;    // VD
constexpr int PP = 1024;   // 32*32
constexpr int HND = 512;
constexpr int EMBD = 300;
constexpr int CIN = 776;   // 256 + 8 + 512

// ---- workspace layout (float element offsets); bf16 buffers are [n][p][c] ----
constexpr size_t SZB = (size_t)NB * PP * CD / 2;             // floats per bf16 NPC buffer
constexpr size_t OF_FEATB = 0;                               // running feature (bf16)
constexpr size_t OF_TB   = 1*SZB;                            // t (bf16)
constexpr size_t OF_KHB  = 2*SZB;                            // kh (bf16)
constexpr size_t OF_VVB  = 3*SZB;                            // vv (bf16)
constexpr size_t OF_AOB  = 4*SZB;                            // attn out (bf16)
constexpr size_t OF_QH   = 7*SZB;                            // qh [s][n][c] fp32
constexpr size_t OF_HNW  = OF_QH  + (size_t)SEQL*NB*CD;      // hnW [r][n][o] fp32
constexpr size_t OF_SCV  = OF_HNW + (size_t)9*NB*CD;         // sconv [p][o] fp32
constexpr size_t OF_WRG  = OF_SCV + (size_t)PP*CD;           // W_region [r][o][c] fp32
constexpr size_t OF_AW   = OF_WRG + (size_t)9*CD*HND;        // conv W A-frags (589,824 bf16)
constexpr size_t OF_PK   = OF_AW  + (size_t)294912;          // linear W B-frags: 5 x 65,536 bf16
constexpr size_t OF_FLAG = OF_PK  + (size_t)163840;          // dtype flag

DEV float bf2f(bf16 v) { return __bfloat162float(v); }
DEV bf16 f2bf(float v) { return __float2bfloat16(v); }

DEV float LD(const void* p, size_t i, int bf) {
  return bf ? __bfloat162float(((const bf16*)p)[i]) : ((const float*)p)[i];
}
DEV int get_bf(const float* ws) { return ((const int*)ws)[OF_FLAG]; }

__global__ void k_detect(const void* g, float* ws) {
  if (threadIdx.x == 0 && blockIdx.x == 0) {
    unsigned w = *(const unsigned*)g;
    ((int*)ws)[OF_FLAG] = ((w & 0xFFFFu) != 0u) ? 1 : 0;
  }
}

// LN reduction: tile[o][x], stride 33; red[512+x]=mean, red[544+x]=rstd, x in [0,32)
DEV void ln_reduce(const float* tile, float* red, int tid) {
  const int x = tid & 31, seg = tid >> 5;
  float s = 0.f, sq = 0.f;
  for (int i = 0; i < 32; ++i) {
    float v = tile[(seg*32 + i)*33 + x];
    s += v; sq += v*v;
  }
  red[seg*32 + x] = s;
  red[256 + seg*32 + x] = sq;
  __syncthreads();
  if (tid < 32) {
    float ts = 0.f, tq = 0.f;
    for (int g = 0; g < 8; ++g) { ts += red[g*32 + tid]; tq += red[256 + g*32 + tid]; }
    float m = ts * (1.f/CD);
    float var = tq * (1.f/CD) - m*m;
    red[512 + tid] = m;
    red[544 + tid] = 1.f / sqrtf(var + 1e-5f);
  }
  __syncthreads();
}

// stage 32 rows x 256 cols bf16 -> LDS As[32][264]
DEV void stageA(const bf16* __restrict__ src, short* __restrict__ As, int tid) {
  const int r = tid >> 3, c0 = (tid & 7)*32;
#pragma unroll
  for (int i = 0; i < 4; ++i) {
    short8 v = *(const short8*)&src[(size_t)r*CD + c0 + i*8];
    *(short8*)&As[r*264 + c0 + i*8] = v;
  }
}

// C[p=32][c=256] = A[32][256] x W^T via MFMA with depth-1 prefetch on A(LDS) and B(global)
DEV void mfma_core_pf(const short* __restrict__ As, const short* __restrict__ PKg,
                      int w, int lane, float4v acc[2][4]) {
  const int xb = lane & 15, quad = lane >> 4;
  const short* base = PKg + (size_t)w*4*8*512 + lane*8;
  short8 bcur[4];
#pragma unroll
  for (int nti = 0; nti < 4; ++nti) bcur[nti] = *(const short8*)&base[(size_t)nti*8*512];
  short8 a0 = *(const short8*)&As[xb*264 + quad*8];
  short8 a1 = *(const short8*)&As[(16+xb)*264 + quad*8];
#pragma unroll
  for (int ch = 0; ch < 8; ++ch) {
    const int chn = (ch + 1) & 7;
    short8 bnxt[4];
#pragma unroll
    for (int nti = 0; nti < 4; ++nti) bnxt[nti] = *(const short8*)&base[(size_t)(nti*8 + chn)*512];
    short8 a0n = *(const short8*)&As[xb*264 + chn*32 + quad*8];
    short8 a1n = *(const short8*)&As[(16+xb)*264 + chn*32 + quad*8];
#pragma unroll
    for (int nti = 0; nti < 4; ++nti) {
      acc[0][nti] = __builtin_amdgcn_mfma_f32_16x16x32_bf16(a0, bcur[nti], acc[0][nti], 0, 0, 0);
      acc[1][nti] = __builtin_amdgcn_mfma_f32_16x16x32_bf16(a1, bcur[nti], acc[1][nti], 0, 0, 0);
    }
#pragma unroll
    for (int nti = 0; nti < 4; ++nti) bcur[nti] = bnxt[nti];
    a0 = a0n; a1 = a1n;
  }
}

// ---------------- prep kernels ----------------

__global__ __launch_bounds__(256) void k_init(const void* __restrict__ f, float* __restrict__ ws) {
  const int bf = get_bf(ws);
  const int b = blockIdx.x;
  const int n = b >> 10, p = b & 1023;
  const int c = threadIdx.x;
  bf16* fb = (bf16*)(ws + OF_FEATB);
  fb[(size_t)b*CD + c] = f2bf(LD(f, ((size_t)n*CD + c)*PP + p, bf));
}

__global__ __launch_bounds__(256) void k_qh(const void* __restrict__ emb, const void* __restrict__ qw,
                                            const void* __restrict__ qb, const void* __restrict__ ipw,
                                            const void* __restrict__ ipb, float* __restrict__ ws) {
  const int bf = get_bf(ws);
  const int b = blockIdx.x, s = b / NB, n = b % NB;
  const int o = threadIdx.x;
  __shared__ float se[EMBD];
  __shared__ float sq[CD];
  for (int i = o; i < EMBD; i += CD) se[i] = LD(emb, ((size_t)n*SEQL + s)*EMBD + i, bf);
  __syncthreads();
  float a = LD(qb, o, bf);
  if (bf) {
    const bf16* wr = (const bf16*)qw + (size_t)o*EMBD;
    for (int c = 0; c < EMBD; ++c) a += se[c]*bf2f(wr[c]);
  } else {
    const float* wr = (const float*)qw + (size_t)o*EMBD;
    for (int c = 0; c < EMBD; ++c) a += se[c]*wr[c];
  }
  sq[o] = fmaxf(a, 0.f);
  __syncthreads();
  float a2 = LD(ipb, o, bf);
  if (bf) {
    const bf16* wq = (const bf16*)ipw + (size_t)o*CD;
    for (int c = 0; c < CD; ++c) a2 += sq[c]*bf2f(wq[c]);
  } else {
    const float* wq = (const float*)ipw + (size_t)o*CD;
    for (int c = 0; c < CD; ++c) a2 += sq[c]*wq[c];
  }
  ws[OF_QH + ((size_t)s*NB + n)*CD + o] = a2;
}

__global__ __launch_bounds__(256) void k_wregion(const void* __restrict__ mw, float* __restrict__ ws) {
  const int bf = get_bf(ws);
  const int gid = blockIdx.x*256 + threadIdx.x;
  const int c = gid & (HND-1);
  const int o = (gid >> 9) & (CD-1);
  const int r = gid >> 17;
  const int ry = r/3, rx = r%3;
  float s = 0.f;
  for (int dy = 0; dy < 3; ++dy) {
    if (ry == 0 && dy == 0) continue;
    if (ry == 2 && dy == 2) continue;
    for (int dx = 0; dx < 3; ++dx) {
      if (rx == 0 && dx == 0) continue;
      if (rx == 2 && dx == 2) continue;
      s += LD(mw, ((size_t)o*CIN + 264 + c)*9 + dy*3 + dx, bf);
    }
  }
  ws[OF_WRG + gid] = s;
}

__global__ __launch_bounds__(256) void k_hnw(const void* __restrict__ hn, float* __restrict__ ws) {
  const int bf = get_bf(ws);
  const int b = blockIdx.x, r = b / NB, n = b % NB;
  const int o = threadIdx.x;
  __shared__ float sh[HND];
  for (int i = o; i < HND; i += CD) sh[i] = LD(hn, (size_t)n*HND + i, bf);
  __syncthreads();
  const float* wr = ws + OF_WRG + ((size_t)r*CD + o)*HND;
  float a = 0.f;
  for (int c = 0; c < HND; ++c) a += sh[c]*wr[c];
  ws[OF_HNW + ((size_t)r*NB + n)*CD + o] = a;
}

DEV float spat(int c, int yy, int xx) {
  switch (c) {
    case 0: return xx*(1.f/16) - 1.f;
    case 1: return yy*(1.f/16) - 1.f;
    case 2: return (xx+1)*(1.f/16) - 1.f;
    case 3: return (yy+1)*(1.f/16) - 1.f;
    case 4: return (xx+0.5f)*(1.f/16) - 1.f;
    case 5: return (yy+0.5f)*(1.f/16) - 1.f;
    default: return 1.f/32;
  }
}

__global__ __launch_bounds__(256) void k_sconv(const void* __restrict__ mw, float* __restrict__ ws) {
  const int bf = get_bf(ws);
  const int p = blockIdx.x, o = threadIdx.x;
  const int y = p >> 5, x = p & 31;
  float a = 0.f;
  for (int c = 0; c < 8; ++c)
    for (int dy = 0; dy < 3; ++dy) {
      int yy = y + dy - 1; if ((unsigned)yy >= 32u) continue;
      for (int dx = 0; dx < 3; ++dx) {
        int xx = x + dx - 1; if ((unsigned)xx >= 32u) continue;
        a += LD(mw, ((size_t)o*CIN + 256 + c)*9 + dy*3 + dx, bf) * spat(c, yy, xx);
      }
    }
  ws[OF_SCV + (size_t)p*CD + o] = a;
}

// conv feat weights -> MFMA A-frag order: AW[it=tap*8+ch][mt][lane][j]
__global__ __launch_bounds__(256) void k_wpack(const void* __restrict__ mw, float* __restrict__ ws) {
  const int bf = get_bf(ws);
  const int idx = blockIdx.x*256 + threadIdx.x;
  const int j = idx & 7;
  const int lane = (idx >> 3) & 63;
  const int mt = (idx >> 9) & 15;
  const int ch = (idx >> 13) & 7;
  const int tap = idx >> 16;
  const int o = mt*16 + (lane & 15);
  const int c = ch*32 + (lane >> 4)*8 + j;
  bf16* aw = (bf16*)(ws + OF_AW);
  aw[idx] = f2bf(LD(mw, ((size_t)o*CIN + c)*9 + tap, bf));
}

// linear weights -> MFMA B-frag order: PK[g][nt][ch][lane][8]; g: 0=Wk 1=Wv 2=Wo 3=W1 4=W2
__global__ __launch_bounds__(256) void k_wpackB(const void* __restrict__ ipw, const void* __restrict__ opw,
                                                const void* __restrict__ l1w, const void* __restrict__ l2w,
                                                float* __restrict__ ws) {
  const int bf = get_bf(ws);
  const int idx = blockIdx.x*256 + threadIdx.x;
  const int j = idx & 7;
  const int lane = (idx >> 3) & 63;
  const int ch = (idx >> 9) & 7;
  const int nt = (idx >> 12) & 15;
  const int g = idx >> 16;
  const int o = nt*16 + (lane & 15);
  const int k = ch*32 + (lane >> 4)*8 + j;
  float v;
  switch (g) {
    case 0: v = LD(ipw, ((size_t)(256 + o))*CD + k, bf); break;
    case 1: v = LD(ipw, ((size_t)(512 + o))*CD + k, bf); break;
    case 2: v = LD(opw, (size_t)o*CD + k, bf);           break;
    case 3: v = LD(l1w, (size_t)o*CD + k, bf);           break;
    default: v = LD(l2w, (size_t)o*CD + k, bf);          break;
  }
  ((bf16*)(ws + OF_PK))[idx] = f2bf(v);
}

// ---------------- per-step kernels ----------------

// FUSED: 3x3 conv (MFMA, pipelined) + relu + LN -> t  ;  then K,V projections from LDS t
__global__ __launch_bounds__(256) void k_convkv(const void* __restrict__ mg, const void* __restrict__ mbv,
                                                const void* __restrict__ ipb, float* __restrict__ ws) {
  __shared__ float smem[13464];            // X3T[3][34][264] bf16 -> reused as tile[256][33]+red
  __shared__ short AsT[32*264];            // t tile in A-stage layout (bf16)
  bf16* Xs = (bf16*)smem;
  const int bfv = get_bf(ws);
  const int b = blockIdx.x, n = b >> 5, y = b & 31;
  const int tid = threadIdx.x;
  const int w = tid >> 6, lane = tid & 63;
  const int xb = lane & 15, quad = lane >> 4;
  const bf16* fb = (const bf16*)(ws + OF_FEATB);

  // ---- stage rows y-1..y+1 zero-padded, transposed: X3T[r][1+x][c] ----
  const short8 zero8 = {0,0,0,0,0,0,0,0};
  if (tid < 192) {
    const int r = tid >> 6, xp = ((tid >> 5) & 1) * 33, c0 = (tid & 31)*8;
    *(short8*)&Xs[(r*34 + xp)*264 + c0] = zero8;
  }
#pragma unroll
  for (int u = 0; u < 12; ++u) {
    const int lin = u*256 + tid;
    const int cgrp = lin & 31, xl = (lin >> 5) & 31, r = lin >> 10;
    const int row = y + r - 1;
    short8 v = zero8;
    if ((unsigned)row < 32u)
      v = *(const short8*)&fb[((size_t)(n*PP + row*32 + xl))*CD + cgrp*8];
    *(short8*)&Xs[(r*34 + 1 + xl)*264 + cgrp*8] = v;
  }
  __syncthreads();

  // ---- conv MFMA K-loop, 72 iters (tap*8+ch), A depth-4 / B depth-2 pipeline ----
  float4v acc[4][2];
#pragma unroll
  for (int mti = 0; mti < 4; ++mti) { acc[mti][0] = (float4v)0.f; acc[mti][1] = (float4v)0.f; }
  const bf16* AW = (const bf16*)(ws + OF_AW);
  const short* Xs16 = (const short*)smem;

#define LDA(IT, DST) do {                                                     \
    const bf16* ap_ = AW + (((size_t)(IT)*16 + w*4)*64 + lane)*8;             \
    _Pragma("unroll")                                                         \
    for (int mti_ = 0; mti_ < 4; ++mti_)                                      \
      (DST)[mti_] = *(const short8*)&ap_[(size_t)mti_*512];                   \
  } while (0)
#define LDB(IT, B0, B1) do {                                                  \
    const int tap_ = (IT) >> 3, ch_ = (IT) & 7;                               \
    const int dy_ = tap_/3, dx_ = tap_ - dy_*3;                               \
    (B0) = *(const short8*)&Xs16[(dy_*34 + xb + dx_)*264 + ch_*32 + quad*8];  \
    (B1) = *(const short8*)&Xs16[(dy_*34 + xb + 16 + dx_)*264 + ch_*32 + quad*8]; \
  } while (0)

  short8 ap4[4][4];
  short8 b0p[2], b1p[2];
#pragma unroll
  for (int d = 0; d < 4; ++d) LDA(d, ap4[d]);
  LDB(0, b0p[0], b1p[0]);
  LDB(1, b0p[1], b1p[1]);
#pragma unroll 1
  for (int itb = 0; itb < 72; itb += 4) {
#pragma unroll
    for (int u = 0; u < 4; ++u) {
      const int it = itb + u;
      short8 b0n, b1n, an[4];
      LDB((it+2)%72, b0n, b1n);
      LDA((it+4)%72, an);
#pragma unroll
      for (int mti = 0; mti < 4; ++mti) {
        acc[mti][0] = __builtin_amdgcn_mfma_f32_16x16x32_bf16(ap4[u][mti], b0p[u&1], acc[mti][0], 0, 0, 0);
        acc[mti][1] = __builtin_amdgcn_mfma_f32_16x16x32_bf16(ap4[u][mti], b1p[u&1], acc[mti][1], 0, 0, 0);
      }
      b0p[u&1] = b0n; b1p[u&1] = b1n;
#pragma unroll
      for (int mti = 0; mti < 4; ++mti) ap4[u][mti] = an[mti];
    }
  }
#undef LDA
#undef LDB
  __syncthreads();

  // ---- tile[o][x] <- frags ----
  float* tile = smem;
  float* red = smem + 8448;
#pragma unroll
  for (int mti = 0; mti < 4; ++mti)
#pragma unroll
    for (int nt = 0; nt < 2; ++nt)
#pragma unroll
      for (int r = 0; r < 4; ++r)
        tile[((w*4 + mti)*16 + quad*4 + r)*33 + nt*16 + xb] = acc[mti][nt][r];
  __syncthreads();

  // ---- + static terms, relu ----
  const int o = tid;
  {
    const int ry = (y == 0) ? 0 : ((y == 31) ? 2 : 1);
    const float* hnw = ws + OF_HNW;
    const float bl = hnw[((size_t)(ry*3+0)*NB + n)*CD + o];
    const float bm = hnw[((size_t)(ry*3+1)*NB + n)*CD + o];
    const float br = hnw[((size_t)(ry*3+2)*NB + n)*CD + o];
    const float* sc = ws + OF_SCV + (size_t)(y*32)*CD + o;
#pragma unroll
    for (int x = 0; x < 32; ++x) {
      float v = tile[o*33 + x] + sc[(size_t)x*CD] + (x == 0 ? bl : (x == 31 ? br : bm));
      tile[o*33 + x] = fmaxf(v, 0.f);
    }
  }
  __syncthreads();
  ln_reduce(tile, red, tid);
  {
    const float g = LD(mg, o, bfv), bb = LD(mbv, o, bfv);
    bf16* tp = (bf16*)(ws + OF_TB) + ((size_t)n*PP + (size_t)y*32)*CD + o;
#pragma unroll
    for (int x = 0; x < 32; ++x) {
      const bf16 tv = f2bf((tile[o*33 + x] - red[512 + x]) * red[544 + x] * g + bb);
      tp[(size_t)x*CD] = tv;                  // global (outproj residual)
      AsT[x*264 + o] = *(const short*)&tv;    // LDS A-tile for K/V
    }
  }
  __syncthreads();

  // ---- K and V projections from AsT ----
  const short* PK = (const short*)(ws + OF_PK);
  const int p0 = y << 5;
#pragma unroll 1
  for (int G = 0; G < 2; ++G) {
    float4v ac2[2][4];
#pragma unroll
    for (int mt = 0; mt < 2; ++mt)
#pragma unroll
      for (int nti = 0; nti < 4; ++nti) ac2[mt][nti] = (float4v)0.f;
    mfma_core_pf(AsT, PK + (size_t)G*65536, w, lane, ac2);
    bf16* dst = (bf16*)(ws + (G ? OF_VVB : OF_KHB)) + ((size_t)n*PP + p0)*CD;
#pragma unroll
    for (int nti = 0; nti < 4; ++nti) {
      const int c = (w*4 + nti)*16 + xb;
      const float bias = LD(ipb, (size_t)(G+1)*256 + c, bfv);
#pragma unroll
      for (int mt = 0; mt < 2; ++mt)
#pragma unroll
        for (int r = 0; r < 4; ++r)
          dst[(size_t)(mt*16 + quad*4 + r)*CD + c] = f2bf(ac2[mt][nti][r] + bias);
    }
  }
}

// cross-batch attention: one wave per (p, h); bf16 K/V, fp32 math
__global__ __launch_bounds__(64) void k_attn(int s, float* __restrict__ ws) {
  __shared__ float SQ[16*132], SK[16*132], SV[16*132], SA[16*20];
  const int p = blockIdx.x >> 1, h = blockIdx.x & 1;
  const int lane = threadIdx.x;
  const bf16* khb = (const bf16*)(ws + OF_KHB);
  const bf16* vvb = (const bf16*)(ws + OF_VVB);
  for (int i = lane; i < 16*128; i += 64) {
    const int l = i >> 7, d = i & 127;
    SQ[l*132 + d] = ws[OF_QH + ((size_t)(s*NB + l))*CD + h*128 + d];
    SK[l*132 + d] = bf2f(khb[((size_t)l*PP + p)*CD + h*128 + d]);
    SV[l*132 + d] = bf2f(vvb[((size_t)l*PP + p)*CD + h*128 + d]);
  }
  __syncthreads();
  const int l = lane >> 2, mg = lane & 3;
  float sc[4];
#pragma unroll
  for (int j = 0; j < 4; ++j) {
    const int m = mg*4 + j;
    float a = 0.f;
    for (int d4 = 0; d4 < 128; d4 += 4) {
      float4 q = *(const float4*)&SQ[l*132 + d4];
      float4 k = *(const float4*)&SK[m*132 + d4];
      a += q.x*k.x + q.y*k.y + q.z*k.z + q.w*k.w;
    }
    sc[j] = a * 0.08838834764831845f;
  }
  float mx = fmaxf(fmaxf(sc[0], sc[1]), fmaxf(sc[2], sc[3]));
  mx = fmaxf(mx, __shfl_xor(mx, 1, 64));
  mx = fmaxf(mx, __shfl_xor(mx, 2, 64));
  float sum = 0.f;
#pragma unroll
  for (int j = 0; j < 4; ++j) { sc[j] = __expf(sc[j] - mx); sum += sc[j]; }
  sum += __shfl_xor(sum, 1, 64);
  sum += __shfl_xor(sum, 2, 64);
  const float inv = 1.f / sum;
#pragma unroll
  for (int j = 0; j < 4; ++j) SA[l*20 + mg*4 + j] = sc[j]*inv;
  __syncthreads();
  float oa[32];
#pragma unroll
  for (int d = 0; d < 32; ++d) oa[d] = 0.f;
  for (int m = 0; m < 16; ++m) {
    const float a = SA[l*20 + m];
#pragma unroll
    for (int d4 = 0; d4 < 8; ++d4) {
      float4 v = *(const float4*)&SV[m*132 + mg*32 + d4*4];
      oa[d4*4+0] += a*v.x; oa[d4*4+1] += a*v.y; oa[d4*4+2] += a*v.z; oa[d4*4+3] += a*v.w;
    }
  }
  bf16* dst = (bf16*)(ws + OF_AOB) + ((size_t)l*PP + p)*CD + h*128 + mg*32;
#pragma unroll
  for (int d = 0; d < 32; ++d) dst[d] = f2bf(oa[d]);
}

// FUSED: fea = LN(t + ao@Wo^T + b); f2a = relu(fea@W1^T+b); out = LN(fea + f2a@W2^T+b); commit
__global__ __launch_bounds__(256) void k_oplin(const void* __restrict__ opb, const void* __restrict__ ng,
                                               const void* __restrict__ nbv, const void* __restrict__ l1b,
                                               const void* __restrict__ l2b, const void* __restrict__ nfg,
                                               const void* __restrict__ nfb, const int* __restrict__ words,
                                               int s, float* __restrict__ ws) {
  __shared__ float tile[256*33 + 576];     // tile + red
  __shared__ short AsA[32*264];            // ao staging, then f2a
  __shared__ short AsF[32*264];            // fea (bf16)
  const int bf = get_bf(ws);
  const int b = blockIdx.x, n = b >> 5, p0 = (b & 31) << 5;
  const int tid = threadIdx.x, w = tid >> 6, lane = tid & 63;
  const int xb = lane & 15, quad = lane >> 4;
  const int o = tid;
  float* red = tile + 8448;
  const short* PK = (const short*)(ws + OF_PK);

  // ---- outproj ----
  stageA((const bf16*)(ws + OF_AOB) + ((size_t)n*PP + p0)*CD, AsA, tid);
  __syncthreads();
  {
    float4v acc[2][4];
#pragma unroll
    for (int mt = 0; mt < 2; ++mt)
#pragma unroll
      for (int nti = 0; nti < 4; ++nti) acc[mt][nti] = (float4v)0.f;
    mfma_core_pf(AsA, PK + (size_t)2*65536, w, lane, acc);
#pragma unroll
    for (int nti = 0; nti < 4; ++nti)
#pragma unroll
      for (int mt = 0; mt < 2; ++mt)
#pragma unroll
        for (int r = 0; r < 4; ++r)
          tile[((w*4 + nti)*16 + xb)*33 + mt*16 + quad*4 + r] = acc[mt][nti][r];
  }
  __syncthreads();
  {
    const float bo = LD(opb, o, bf);
    const bf16* tb = (const bf16*)(ws + OF_TB) + ((size_t)n*PP + p0)*CD + o;
#pragma unroll
    for (int x = 0; x < 32; ++x)
      tile[o*33 + x] += bo + bf2f(tb[(size_t)x*CD]);
  }
  __syncthreads();
  ln_reduce(tile, red, tid);
  {
    const float g = LD(ng, o, bf), bb = LD(nbv, o, bf);
#pragma unroll
    for (int x = 0; x < 32; ++x) {
      const bf16 fv = f2bf((tile[o*33 + x] - red[512 + x]) * red[544 + x] * g + bb);
      AsF[x*264 + o] = *(const short*)&fv;
    }
  }
  __syncthreads();

  // ---- lin1: f2a frags -> AsA (bf16 [x][c]) ----
  {
    float4v acc[2][4];
#pragma unroll
    for (int mt = 0; mt < 2; ++mt)
#pragma unroll
      for (int nti = 0; nti < 4; ++nti) acc[mt][nti] = (float4v)0.f;
    mfma_core_pf(AsF, PK + (size_t)3*65536, w, lane, acc);
    __syncthreads();   // AsA free (outproj reads done long ago); ensure no one still staging
#pragma unroll
    for (int nti = 0; nti < 4; ++nti) {
      const int c = (w*4 + nti)*16 + xb;
      const float bias = LD(l1b, c, bf);
#pragma unroll
      for (int mt = 0; mt < 2; ++mt)
#pragma unroll
        for (int r = 0; r < 4; ++r) {
          const bf16 fv = f2bf(fmaxf(acc[mt][nti][r] + bias, 0.f));
          AsA[(mt*16 + quad*4 + r)*264 + c] = *(const short*)&fv;
        }
    }
  }
  __syncthreads();

  // ---- lin2 + LN + conditional commit ----
  {
    float4v acc[2][4];
#pragma unroll
    for (int mt = 0; mt < 2; ++mt)
#pragma unroll
      for (int nti = 0; nti < 4; ++nti) acc[mt][nti] = (float4v)0.f;
    mfma_core_pf(AsA, PK + (size_t)4*65536, w, lane, acc);
    __syncthreads();
#pragma unroll
    for (int nti = 0; nti < 4; ++nti)
#pragma unroll
      for (int mt = 0; mt < 2; ++mt)
#pragma unroll
        for (int r = 0; r < 4; ++r)
          tile[((w*4 + nti)*16 + xb)*33 + mt*16 + quad*4 + r] = acc[mt][nti][r];
  }
  __syncthreads();
  {
    const float bb = LD(l2b, o, bf);
#pragma unroll
    for (int x = 0; x < 32; ++x) {
      bf16 fv; *(short*)&fv = AsF[x*264 + o];
      tile[o*33 + x] += bb + bf2f(fv);
    }
  }
  __syncthreads();
  ln_reduce(tile, red, tid);
  if (words[s] != 0) {
    const float g = LD(nfg, o, bf), b2 = LD(nfb, o, bf);
    bf16* fbd = (bf16*)(ws + OF_FEATB) + ((size_t)n*PP + p0)*CD + o;
#pragma unroll
    for (int x = 0; x < 32; ++x)
      fbd[(size_t)x*CD] = f2bf((tile[o*33 + x] - red[512 + x]) * red[544 + x] * g + b2);
  }
}

// output [n][c][p] from bf16 feat [n][p][c]
__global__ __launch_bounds__(256) void k_final(const float* __restrict__ ws, void* __restrict__ out) {
  const int bf = get_bf(ws);
  const size_t i = (size_t)blockIdx.x*256 + threadIdx.x;
  const int n = (int)(i >> 18), c = (int)((i >> 10) & 255), p = (int)(i & 1023);
  const bf16* fb = (const bf16*)(ws + OF_FEATB);
  float v = bf2f(fb[((size_t)(n*PP + p))*CD + c]);
  if (bf) ((bf16*)out)[i] = f2bf(v);
  else    ((float*)out)[i] = v;
}

extern "C" void kernel_launch(void* const* d_in, const int* in_sizes, int n_in,
                              void* d_out, int out_size, void* d_ws, size_t ws_size,
                              hipStream_t stream) {
  (void)in_sizes; (void)n_in; (void)out_size; (void)ws_size;
  const void* hn      = d_in[1];
  const void* feature = d_in[2];
  const void* emb     = d_in[3];
  const int*  words   = (const int*)d_in[4];
  const void* qw  = d_in[5];
  const void* qb  = d_in[6];
  const void* mw  = d_in[7];
  const void* mg  = d_in[8];
  const void* mb  = d_in[9];
  const void* ipw = d_in[10];
  const void* ipb = d_in[11];
  const void* opw = d_in[12];
  const void* opb = d_in[13];
  const void* ng  = d_in[14];
  const void* nb  = d_in[15];
  const void* l1w = d_in[16];
  const void* l1b = d_in[17];
  const void* l2w = d_in[18];
  const void* l2b = d_in[19];
  const void* nfg = d_in[20];
  const void* nfb = d_in[21];
  float* ws = (float*)d_ws;

  k_detect<<<1, 64, 0, stream>>>(mg, ws);
  k_init<<<NB*PP, 256, 0, stream>>>(feature, ws);
  k_qh<<<SEQL*NB, 256, 0, stream>>>(emb, qw, qb, ipw, ipb, ws);
  k_wregion<<<(9*CD*HND)/256, 256, 0, stream>>>(mw, ws);
  k_hnw<<<9*NB, 256, 0, stream>>>(hn, ws);
  k_sconv<<<PP, 256, 0, stream>>>(mw, ws);
  k_wpack<<<(9*8*16*64*8)/256, 256, 0, stream>>>(mw, ws);
  k_wpackB<<<(5*65536)/256, 256, 0, stream>>>(ipw, opw, l1w, l2w, ws);

  for (int s = 0; s < SEQL; ++s) {
    k_convkv<<<NB*32, 256, 0, stream>>>(mg, mb, ipb, ws);
    k_attn<<<PP*2, 64, 0, stream>>>(s, ws);
    k_oplin<<<NB*32, 256, 0, stream>>>(opb, ng, nb, l1b, l2b, nfg, nfb, words, s, ws);
  }
  k_final<<<NB*CD*PP/256, 256, 0, stream>>>(ws, (void*)d_out);
}